// Round 5
// baseline (674.460 us; speedup 1.0000x reference)
//
#include <hip/hip_runtime.h>
#include <hip/hip_bf16.h>
#include <stdint.h>

typedef __bf16 bf16x8 __attribute__((ext_vector_type(8)));
typedef float f32x4 __attribute__((ext_vector_type(4)));
typedef float f32x16 __attribute__((ext_vector_type(16)));
typedef float f32x4v __attribute__((ext_vector_type(4)));
typedef unsigned short u16;
typedef unsigned int u32;
typedef u16 u16x8 __attribute__((ext_vector_type(8)));
typedef u32 u32x4 __attribute__((ext_vector_type(4)));

#define B_ 2
#define S_ 2048
#define HID_ 2048
#define H_ 16
#define HK_ 4
#define D_ 128
#define NQKV_ 3072

__device__ __forceinline__ u16 f2bf(float f) {
  u32 u = __builtin_bit_cast(u32, f);
  u32 r = (u + 0x7fffu + ((u >> 16) & 1u)) >> 16;
  return (u16)r;
}
__device__ __forceinline__ float bf2f(u16 v) {
  u32 u = ((u32)v) << 16;
  return __builtin_bit_cast(float, u);
}
__device__ __forceinline__ u32 cvtpk(float lo, float hi) {
  u32 r;
  asm("v_cvt_pk_bf16_f32 %0, %1, %2" : "=v"(r) : "v"(lo), "v"(hi));
  return r;
}
__device__ __forceinline__ void gload_lds16(const void* g, void* l) {
  __builtin_amdgcn_global_load_lds((const __attribute__((address_space(1))) void*)g,
                                   (__attribute__((address_space(3))) void*)l, 16, 0, 0);
}

// ---------------- f32 -> bf16 bulk convert ----------------
__global__ __launch_bounds__(256) void k_f32_to_bf16(const float* __restrict__ in,
                                                     u16* __restrict__ out, int n8) {
  for (int i = blockIdx.x * 256 + threadIdx.x; i < n8; i += gridDim.x * 256) {
    const f32x4v* p = (const f32x4v*)(in + (size_t)i * 8);
    f32x4v a = p[0], b = p[1];
    u16x8 w;
    w[0] = f2bf(a[0]); w[1] = f2bf(a[1]); w[2] = f2bf(a[2]); w[3] = f2bf(a[3]);
    w[4] = f2bf(b[0]); w[5] = f2bf(b[1]); w[6] = f2bf(b[2]); w[7] = f2bf(b[3]);
    *(u16x8*)(out + (size_t)i * 8) = w;
  }
}

// ---------------- 8-phase deep-pipelined GEMM: C = A[M][K] . B[N][K]^T + bias ----
template <int ISSUES>
__device__ __forceinline__ void stage_half(const u16* __restrict__ src, int K, char* ldsb, int tid) {
#pragma unroll
  for (int i = 0; i < ISSUES; ++i) {
    int off = i * 8192 + tid * 16;
    int r = off >> 7, cb = off & 127;
    int scb = cb ^ ((r & 7) << 4);
    gload_lds16((const char*)(src + (size_t)r * K) + scb, ldsb + i * 8192 + (tid & ~63) * 16);
  }
}

template <int BM, typename CT>
__global__ __launch_bounds__(512, 1) void k_gemm8p(const u16* __restrict__ A, const u16* __restrict__ Bm,
                                                   const float* __restrict__ bias, CT* __restrict__ C,
                                                   int M, int N, int K) {
  constexpr int HAR = BM / 2;            // rows per A half-tile
  constexpr int AHB = HAR * 128;         // bytes per A half-tile
  constexpr int AISS = AHB / 8192;       // gload issues per A half
  constexpr int MREP = BM / 32;          // 16-row frags per wave
  constexpr int MQ = MREP / 4;           // m-frags per phase
  constexpr int DB = 2 * AHB + 32768;    // dbuf stride
  __shared__ __attribute__((aligned(16))) char lds[2 * DB];
  const int tid = threadIdx.x, lane = tid & 63;
  const int wid = tid >> 6, wm = wid >> 2, wn = wid & 3;
  const int l15 = lane & 15, l4 = lane >> 4;
  const int row0 = blockIdx.y * BM, col0 = blockIdx.x * 256;
  const int NT = K >> 6;

  f32x4 acc[MREP][4] = {};

  auto stageA = [&](int t, int h) {
    stage_half<AISS>(A + (size_t)(row0 + h * HAR) * K + t * 64, K, lds + (t & 1) * DB + h * AHB, tid);
  };
  auto stageB = [&](int t, int h) {
    stage_half<2>(Bm + (size_t)(col0 + h * 128) * K + t * 64, K, lds + (t & 1) * DB + 2 * AHB + h * 16384, tid);
  };

  stageA(0, 0); stageA(0, 1); stageB(0, 0); stageB(0, 1);
  if (NT > 1) { stageB(1, 0); stageB(1, 1); }
  if (NT > 1) asm volatile("s_waitcnt vmcnt(4)" ::: "memory");
  else        asm volatile("s_waitcnt vmcnt(0)" ::: "memory");
  __builtin_amdgcn_s_barrier();

  const char* myA = lds + wm * AHB;
  const char* myB = lds + 2 * AHB + (wn >> 1) * 16384;
  const int rBb = (wn & 1) * 64;

  for (int t = 0; t < NT; ++t) {
    const int d = t & 1;
    const char* Ab = myA + d * DB;
    const char* Bb = myB + d * DB;
    bf16x8 bfr[4][2];
#pragma unroll
    for (int j = 0; j < 4; ++j) {
      if (j == 0) {
#pragma unroll
        for (int n = 0; n < 4; ++n)
#pragma unroll
          for (int ks = 0; ks < 2; ++ks) {
            int r = rBb + n * 16 + l15;
            bfr[n][ks] = *(const bf16x8*)(Bb + r * 128 + ((ks * 64 + l4 * 16) ^ ((r & 7) << 4)));
          }
      }
      bf16x8 afr[MQ][2];
#pragma unroll
      for (int mq = 0; mq < MQ; ++mq)
#pragma unroll
        for (int ks = 0; ks < 2; ++ks) {
          int r = (j * MQ + mq) * 16 + l15;
          afr[mq][ks] = *(const bf16x8*)(Ab + r * 128 + ((ks * 64 + l4 * 16) ^ ((r & 7) << 4)));
        }
      if (j == 0) { if (t + 1 < NT) stageA(t + 1, 0); }
      else if (j == 1) { if (t + 1 < NT) stageA(t + 1, 1); }
      else if (j == 2) { if (t + 2 < NT) stageB(t + 2, 0); }
      else {
        if (t + 2 < NT) { stageB(t + 2, 1); asm volatile("s_waitcnt vmcnt(4)" ::: "memory"); }
        else             asm volatile("s_waitcnt vmcnt(0)" ::: "memory");
      }
      __builtin_amdgcn_s_barrier();
      asm volatile("s_waitcnt lgkmcnt(0)" ::: "memory");
      __builtin_amdgcn_s_setprio(1);
#pragma unroll
      for (int mq = 0; mq < MQ; ++mq)
#pragma unroll
        for (int ks = 0; ks < 2; ++ks)
#pragma unroll
          for (int n = 0; n < 4; ++n)
            acc[j * MQ + mq][n] =
                __builtin_amdgcn_mfma_f32_16x16x32_bf16(afr[mq][ks], bfr[n][ks], acc[j * MQ + mq][n], 0, 0, 0);
      __builtin_amdgcn_s_setprio(0);
      __builtin_amdgcn_s_barrier();
    }
  }

#pragma unroll
  for (int m = 0; m < MREP; ++m) {
    int grow = row0 + wm * HAR + m * 16 + l4 * 4;
#pragma unroll
    for (int n = 0; n < 4; ++n) {
      int gcol = col0 + wn * 64 + n * 16 + l15;
      float bv = bias[gcol];
#pragma unroll
      for (int r2 = 0; r2 < 4; ++r2) {
        float v = acc[m][n][r2] + bv;
        if constexpr (sizeof(CT) == 2) C[(size_t)(grow + r2) * N + gcol] = (CT)f2bf(v);
        else                           C[(size_t)(grow + r2) * N + gcol] = v;
      }
    }
  }
}

// ---------------- RoPE + split + layout (qkv bf16) ----------------
__global__ __launch_bounds__(256) void k_rope_split(const u16* __restrict__ qkv,
                                                    const float* __restrict__ cosb,
                                                    const float* __restrict__ sinb,
                                                    u16* __restrict__ Qb, u16* __restrict__ Kb,
                                                    u16* __restrict__ Vt) {
  const int bs = blockIdx.x;
  const int b = bs >> 11, s = bs & 2047;
  const size_t base = (size_t)bs * NQKV_;
  const size_t cs = (size_t)bs * D_;
  const float qscale = 0.08838834764831845f;  // 1/sqrt(128)
  for (int p = threadIdx.x; p < H_ * 64; p += 256) {
    int h = p >> 6, d = p & 63;
    float f1 = bf2f(qkv[base + h * D_ + d]);
    float f2 = bf2f(qkv[base + h * D_ + 64 + d]);
    float c1 = cosb[cs + d], s1 = sinb[cs + d];
    float c2 = cosb[cs + 64 + d], s2 = sinb[cs + 64 + d];
    size_t o = ((size_t)(b * H_ + h) * S_ + s) * D_ + d;
    Qb[o] = f2bf((f1 * c1 - f2 * s1) * qscale);
    Qb[o + 64] = f2bf((f2 * c2 + f1 * s2) * qscale);
  }
  for (int p = threadIdx.x; p < HK_ * 64; p += 256) {
    int hk = p >> 6, d = p & 63;
    float f1 = bf2f(qkv[base + H_ * D_ + hk * D_ + d]);
    float f2 = bf2f(qkv[base + H_ * D_ + hk * D_ + 64 + d]);
    float c1 = cosb[cs + d], s1 = sinb[cs + d];
    float c2 = cosb[cs + 64 + d], s2 = sinb[cs + 64 + d];
    size_t o = ((size_t)(b * HK_ + hk) * S_ + s) * D_ + d;
    Kb[o] = f2bf(f1 * c1 - f2 * s1);
    Kb[o + 64] = f2bf(f2 * c2 + f1 * s2);
  }
  for (int p = threadIdx.x; p < HK_ * D_; p += 256) {
    int hk = p >> 7, d = p & 127;
    Vt[((size_t)(b * HK_ + hk) * D_ + d) * S_ + s] = qkv[base + H_ * D_ + HK_ * D_ + hk * D_ + d];
  }
}

// ---------------- flash attention: 4 waves x 32 q-rows (q-tile 128), 32x32 MFMA,
//                  swapped QK^T, in-register softmax, O^T = V^T . P^T
//                  grid 512 blocks -> 2 blocks/CU residency ----------------
__global__ __launch_bounds__(256, 4) void k_attn(const u16* __restrict__ Qb, const u16* __restrict__ Kb,
                                                 const u16* __restrict__ Vt, u16* __restrict__ Ob) {
  __shared__ __attribute__((aligned(16))) char lds[32768];
  char* lKc = lds;            // K tile [64 key][128 d] bf16, XOR (row&15)<<4
  char* lVc = lds + 16384;    // V^T tile [128 d][64 key] bf16, XOR (row&7)<<4
  const int qt = blockIdx.x;  // 0..15
  const int bh = blockIdx.y;  // 0..31
  const int b = bh >> 4, h = bh & 15, hk = h >> 2;
  const int tid = threadIdx.x, lane = tid & 63, wid = tid >> 6;
  const int l31 = lane & 31, hi = lane >> 5;

  const int qrow = qt * 128 + wid * 32 + l31;
  const u16* qptr = Qb + ((size_t)(b * H_ + h) * S_ + qrow) * D_;
  bf16x8 qf[8];
#pragma unroll
  for (int ks = 0; ks < 8; ++ks) qf[ks] = *(const bf16x8*)(qptr + ks * 16 + hi * 8);

  const u16* kbase = Kb + (size_t)(b * HK_ + hk) * S_ * D_;
  const u16* vbase = Vt + (size_t)(b * HK_ + hk) * D_ * S_;

  // staging: 256 threads x 4 slots of 16B each for K (16KB) and V^T (16KB)
  int krow[4], kc[4], vrow[4], vc[4];
#pragma unroll
  for (int i = 0; i < 4; ++i) {
    int s = tid + i * 256;
    krow[i] = s >> 4; kc[i] = s & 15;
    vrow[i] = s >> 3; vc[i] = s & 7;
  }

  f32x16 o[4] = {};
  float mrun = -1e30f, lrun = 0.f;

  bf16x8 kreg[4], vreg[4];
#pragma unroll
  for (int i = 0; i < 4; ++i) {
    kreg[i] = *(const bf16x8*)(kbase + (size_t)krow[i] * D_ + kc[i] * 8);
    vreg[i] = *(const bf16x8*)(vbase + (size_t)vrow[i] * S_ + vc[i] * 8);
  }
#pragma unroll
  for (int i = 0; i < 4; ++i) {
    *(bf16x8*)(lKc + ((krow[i] * 256 + kc[i] * 16) ^ ((krow[i] & 15) << 4))) = kreg[i];
    *(bf16x8*)(lVc + ((vrow[i] * 128 + vc[i] * 16) ^ ((vrow[i] & 7) << 4))) = vreg[i];
  }
  __syncthreads();

  for (int kt = 0; kt < 32; ++kt) {
    // T14: issue next tile's global loads early; write to LDS after the barrier
    if (kt < 31) {
#pragma unroll
      for (int i = 0; i < 4; ++i) {
        kreg[i] = *(const bf16x8*)(kbase + (size_t)((kt + 1) * 64 + krow[i]) * D_ + kc[i] * 8);
        vreg[i] = *(const bf16x8*)(vbase + (size_t)vrow[i] * S_ + (kt + 1) * 64 + vc[i] * 8);
      }
    }

    f32x16 sc[2] = {};
    __builtin_amdgcn_s_setprio(1);
#pragma unroll
    for (int ks = 0; ks < 8; ++ks) {
#pragma unroll
      for (int T = 0; T < 2; ++T) {
        int row = T * 32 + l31;
        bf16x8 kf = *(const bf16x8*)(lKc + ((row * 256 + ks * 32 + hi * 16) ^ ((row & 15) << 4)));
        sc[T] = __builtin_amdgcn_mfma_f32_32x32x16_bf16(kf, qf[ks], sc[T], 0, 0, 0);
      }
    }
    __builtin_amdgcn_s_setprio(0);

    float pmax = sc[0][0];
#pragma unroll
    for (int r = 1; r < 16; ++r) pmax = fmaxf(pmax, sc[0][r]);
#pragma unroll
    for (int r = 0; r < 16; ++r) pmax = fmaxf(pmax, sc[1][r]);
    pmax = fmaxf(pmax, __shfl_xor(pmax, 32));
    if (__any(pmax > mrun + 8.f)) {   // T13 defer-max
      float mn = fmaxf(mrun, pmax);
      float alpha = __expf(mrun - mn);
      mrun = mn;
      lrun *= alpha;
#pragma unroll
      for (int dt = 0; dt < 4; ++dt)
#pragma unroll
        for (int r = 0; r < 16; ++r) o[dt][r] *= alpha;
    }
    float rs = 0.f;
#pragma unroll
    for (int T = 0; T < 2; ++T)
#pragma unroll
      for (int r = 0; r < 16; ++r) {
        float p = __expf(sc[T][r] - mrun);
        sc[T][r] = p;
        rs += p;
      }
    rs += __shfl_xor(rs, 32);
    lrun += rs;

    bf16x8 pf[4];
#pragma unroll
    for (int T = 0; T < 2; ++T) {
#pragma unroll
      for (int g = 0; g < 2; ++g) {
        u32 a0 = cvtpk(sc[T][8 * g + 0], sc[T][8 * g + 1]);
        u32 a1 = cvtpk(sc[T][8 * g + 2], sc[T][8 * g + 3]);
        u32 a2 = cvtpk(sc[T][8 * g + 4], sc[T][8 * g + 5]);
        u32 a3 = cvtpk(sc[T][8 * g + 6], sc[T][8 * g + 7]);
        u32 x0 = (u32)__shfl_xor((int)a0, 32);
        u32 x1 = (u32)__shfl_xor((int)a1, 32);
        u32 x2 = (u32)__shfl_xor((int)a2, 32);
        u32 x3 = (u32)__shfl_xor((int)a3, 32);
        u32 s0 = hi ? x2 : a0;
        u32 s1 = hi ? x3 : a1;
        u32 s2 = hi ? a2 : x0;
        u32 s3 = hi ? a3 : x1;
        u32x4 w = {s0, s1, s2, s3};
        pf[T * 2 + g] = __builtin_bit_cast(bf16x8, w);
      }
    }

    __builtin_amdgcn_s_setprio(1);
#pragma unroll
    for (int ks2 = 0; ks2 < 4; ++ks2) {
#pragma unroll
      for (int dt = 0; dt < 4; ++dt) {
        int row = dt * 32 + l31;
        bf16x8 vf = *(const bf16x8*)(lVc + ((row * 128 + ks2 * 32 + hi * 16) ^ ((row & 7) << 4)));
        o[dt] = __builtin_amdgcn_mfma_f32_32x32x16_bf16(vf, pf[ks2], o[dt], 0, 0, 0);
      }
    }
    __builtin_amdgcn_s_setprio(0);

    __syncthreads();
    if (kt < 31) {
#pragma unroll
      for (int i = 0; i < 4; ++i) {
        *(bf16x8*)(lKc + ((krow[i] * 256 + kc[i] * 16) ^ ((krow[i] & 15) << 4))) = kreg[i];
        *(bf16x8*)(lVc + ((vrow[i] * 128 + vc[i] * 16) ^ ((vrow[i] & 7) << 4))) = vreg[i];
      }
    }
    __syncthreads();
  }

  // epilogue: O^T -> O via per-wave LDS region (8KB each, reuses K/V space)
  float inv = 1.0f / lrun;
  char* myreg = lds + wid * 8192;  // [32 q][128 d] bf16, XOR (q&15)<<4 on byte-in-row
#pragma unroll
  for (int dt = 0; dt < 4; ++dt)
#pragma unroll
    for (int t = 0; t < 8; ++t) {
      u32 w = cvtpk(o[dt][2 * t] * inv, o[dt][2 * t + 1] * inv);
      int d0 = dt * 32 + 2 * (t & 1) + 8 * (t >> 1) + 4 * hi;
      *(u32*)(myreg + ((l31 * 256 + d0 * 2) ^ ((l31 & 15) << 4))) = w;
    }
  asm volatile("s_waitcnt lgkmcnt(0)");
  {
    int q = lane >> 1, hf = lane & 1;
    int srow = qt * 128 + wid * 32 + q;
    u16* orow = Ob + ((size_t)(b * S_ + srow)) * HID_ + h * 128 + hf * 64;
#pragma unroll
    for (int i = 0; i < 8; ++i) {
      bf16x8 vv = *(const bf16x8*)(myreg + ((q * 256 + hf * 128 + i * 16) ^ ((q & 15) << 4)));
      *(bf16x8*)(orow + i * 8) = vv;
    }
  }
}

extern "C" void kernel_launch(void* const* d_in, const int* in_sizes, int n_in,
                              void* d_out, int out_size, void* d_ws, size_t ws_size,
                              hipStream_t stream) {
  const float* hs = (const float*)d_in[0];
  const float* cosb = (const float*)d_in[1];
  const float* sinb = (const float*)d_in[2];
  const float* w_qkv = (const float*)d_in[3];
  const float* b_qkv = (const float*)d_in[4];
  const float* w_o = (const float*)d_in[5];
  const float* b_o = (const float*)d_in[6];
  float* out = (float*)d_out;

  char* ws = (char*)d_ws;
  u16* Xb    = (u16*)ws;                          // 16,777,216 B (reused as attn_out)
  u16* Wqkvb = (u16*)(ws + 16777216);             // 12,582,912 B
  u16* Wob   = (u16*)(ws + 29360128);             //  8,388,608 B
  u16* qkvb  = (u16*)(ws + 37748736);             // 25,165,824 B (bf16)
  u16* Qb    = (u16*)(ws + 62914560);             // 16,777,216 B
  u16* Kb    = (u16*)(ws + 79691776);             //  4,194,304 B
  u16* Vt    = (u16*)(ws + 83886080);             //  4,194,304 B  (total 88,080,384 B)
  u16* Ob = Xb;

  hipLaunchKernelGGL(k_f32_to_bf16, dim3(2048), dim3(256), 0, stream, hs, Xb, (B_ * S_ * HID_) / 8);
  hipLaunchKernelGGL(k_f32_to_bf16, dim3(1536), dim3(256), 0, stream, w_qkv, Wqkvb, (NQKV_ * HID_) / 8);
  hipLaunchKernelGGL(k_f32_to_bf16, dim3(1024), dim3(256), 0, stream, w_o, Wob, (HID_ * HID_) / 8);
  hipLaunchKernelGGL((k_gemm8p<256, u16>), dim3(NQKV_ / 256, (B_ * S_) / 256), dim3(512), 0, stream,
                     Xb, Wqkvb, b_qkv, qkvb, B_ * S_, NQKV_, HID_);
  hipLaunchKernelGGL(k_rope_split, dim3(B_ * S_), dim3(256), 0, stream, qkvb, cosb, sinb, Qb, Kb, Vt);
  hipLaunchKernelGGL(k_attn, dim3(S_ / 128, B_ * H_), dim3(256), 0, stream, Qb, Kb, Vt, Ob);
  hipLaunchKernelGGL((k_gemm8p<128, float>), dim3(HID_ / 256, (B_ * S_) / 128), dim3(512), 0, stream,
                     Ob, Wob, b_o, out, B_ * S_, HID_, HID_);
}

// Round 6
// 546.414 us; speedup vs baseline: 1.2343x; 1.2343x over previous
//
#include <hip/hip_runtime.h>
#include <hip/hip_bf16.h>
#include <stdint.h>

typedef __bf16 bf16x8 __attribute__((ext_vector_type(8)));
typedef float f32x4 __attribute__((ext_vector_type(4)));
typedef float f32x16 __attribute__((ext_vector_type(16)));
typedef float f32x4v __attribute__((ext_vector_type(4)));
typedef unsigned short u16;
typedef unsigned int u32;
typedef u16 u16x8 __attribute__((ext_vector_type(8)));
typedef u32 u32x4 __attribute__((ext_vector_type(4)));

#define B_ 2
#define S_ 2048
#define HID_ 2048
#define H_ 16
#define HK_ 4
#define D_ 128
#define NQKV_ 3072

__device__ __forceinline__ u16 f2bf(float f) {
  u32 u = __builtin_bit_cast(u32, f);
  u32 r = (u + 0x7fffu + ((u >> 16) & 1u)) >> 16;
  return (u16)r;
}
__device__ __forceinline__ float bf2f(u16 v) {
  u32 u = ((u32)v) << 16;
  return __builtin_bit_cast(float, u);
}
__device__ __forceinline__ u32 cvtpk(float lo, float hi) {
  u32 r;
  asm("v_cvt_pk_bf16_f32 %0, %1, %2" : "=v"(r) : "v"(lo), "v"(hi));
  return r;
}
__device__ __forceinline__ void gload_lds16(const void* g, void* l) {
  __builtin_amdgcn_global_load_lds((const __attribute__((address_space(1))) void*)g,
                                   (__attribute__((address_space(3))) void*)l, 16, 0, 0);
}

// ---------------- f32 -> bf16 bulk convert ----------------
__global__ __launch_bounds__(256) void k_f32_to_bf16(const float* __restrict__ in,
                                                     u16* __restrict__ out, int n8) {
  for (int i = blockIdx.x * 256 + threadIdx.x; i < n8; i += gridDim.x * 256) {
    const f32x4v* p = (const f32x4v*)(in + (size_t)i * 8);
    f32x4v a = p[0], b = p[1];
    u16x8 w;
    w[0] = f2bf(a[0]); w[1] = f2bf(a[1]); w[2] = f2bf(a[2]); w[3] = f2bf(a[3]);
    w[4] = f2bf(b[0]); w[5] = f2bf(b[1]); w[6] = f2bf(b[2]); w[7] = f2bf(b[3]);
    *(u16x8*)(out + (size_t)i * 8) = w;
  }
}

// ---------------- 8-phase deep-pipelined GEMM: C = A[M][K] . B[N][K]^T + bias ----
template <int ISSUES>
__device__ __forceinline__ void stage_half(const u16* __restrict__ src, int K, char* ldsb, int tid) {
#pragma unroll
  for (int i = 0; i < ISSUES; ++i) {
    int off = i * 8192 + tid * 16;
    int r = off >> 7, cb = off & 127;
    int scb = cb ^ ((r & 7) << 4);
    gload_lds16((const char*)(src + (size_t)r * K) + scb, ldsb + i * 8192 + (tid & ~63) * 16);
  }
}

template <int BM, typename CT>
__global__ __launch_bounds__(512, 1) void k_gemm8p(const u16* __restrict__ A, const u16* __restrict__ Bm,
                                                   const float* __restrict__ bias, CT* __restrict__ C,
                                                   int M, int N, int K) {
  constexpr int HAR = BM / 2;            // rows per A half-tile
  constexpr int AHB = HAR * 128;         // bytes per A half-tile
  constexpr int AISS = AHB / 8192;       // gload issues per A half
  constexpr int MREP = BM / 32;          // 16-row frags per wave
  constexpr int MQ = MREP / 4;           // m-frags per phase
  constexpr int DB = 2 * AHB + 32768;    // dbuf stride
  __shared__ __attribute__((aligned(16))) char lds[2 * DB];
  const int tid = threadIdx.x, lane = tid & 63;
  const int wid = tid >> 6, wm = wid >> 2, wn = wid & 3;
  const int l15 = lane & 15, l4 = lane >> 4;
  const int row0 = blockIdx.y * BM, col0 = blockIdx.x * 256;
  const int NT = K >> 6;

  f32x4 acc[MREP][4] = {};

  auto stageA = [&](int t, int h) {
    stage_half<AISS>(A + (size_t)(row0 + h * HAR) * K + t * 64, K, lds + (t & 1) * DB + h * AHB, tid);
  };
  auto stageB = [&](int t, int h) {
    stage_half<2>(Bm + (size_t)(col0 + h * 128) * K + t * 64, K, lds + (t & 1) * DB + 2 * AHB + h * 16384, tid);
  };

  stageA(0, 0); stageA(0, 1); stageB(0, 0); stageB(0, 1);
  if (NT > 1) { stageB(1, 0); stageB(1, 1); }
  if (NT > 1) asm volatile("s_waitcnt vmcnt(4)" ::: "memory");
  else        asm volatile("s_waitcnt vmcnt(0)" ::: "memory");
  __builtin_amdgcn_s_barrier();

  const char* myA = lds + wm * AHB;
  const char* myB = lds + 2 * AHB + (wn >> 1) * 16384;
  const int rBb = (wn & 1) * 64;

  for (int t = 0; t < NT; ++t) {
    const int d = t & 1;
    const char* Ab = myA + d * DB;
    const char* Bb = myB + d * DB;
    bf16x8 bfr[4][2];
#pragma unroll
    for (int j = 0; j < 4; ++j) {
      if (j == 0) {
#pragma unroll
        for (int n = 0; n < 4; ++n)
#pragma unroll
          for (int ks = 0; ks < 2; ++ks) {
            int r = rBb + n * 16 + l15;
            bfr[n][ks] = *(const bf16x8*)(Bb + r * 128 + ((ks * 64 + l4 * 16) ^ ((r & 7) << 4)));
          }
      }
      bf16x8 afr[MQ][2];
#pragma unroll
      for (int mq = 0; mq < MQ; ++mq)
#pragma unroll
        for (int ks = 0; ks < 2; ++ks) {
          int r = (j * MQ + mq) * 16 + l15;
          afr[mq][ks] = *(const bf16x8*)(Ab + r * 128 + ((ks * 64 + l4 * 16) ^ ((r & 7) << 4)));
        }
      if (j == 0) { if (t + 1 < NT) stageA(t + 1, 0); }
      else if (j == 1) { if (t + 1 < NT) stageA(t + 1, 1); }
      else if (j == 2) { if (t + 2 < NT) stageB(t + 2, 0); }
      else {
        if (t + 2 < NT) { stageB(t + 2, 1); asm volatile("s_waitcnt vmcnt(4)" ::: "memory"); }
        else             asm volatile("s_waitcnt vmcnt(0)" ::: "memory");
      }
      __builtin_amdgcn_s_barrier();
      asm volatile("s_waitcnt lgkmcnt(0)" ::: "memory");
      __builtin_amdgcn_s_setprio(1);
#pragma unroll
      for (int mq = 0; mq < MQ; ++mq)
#pragma unroll
        for (int ks = 0; ks < 2; ++ks)
#pragma unroll
          for (int n = 0; n < 4; ++n)
            acc[j * MQ + mq][n] =
                __builtin_amdgcn_mfma_f32_16x16x32_bf16(afr[mq][ks], bfr[n][ks], acc[j * MQ + mq][n], 0, 0, 0);
      __builtin_amdgcn_s_setprio(0);
      __builtin_amdgcn_s_barrier();
    }
  }

#pragma unroll
  for (int m = 0; m < MREP; ++m) {
    int grow = row0 + wm * HAR + m * 16 + l4 * 4;
#pragma unroll
    for (int n = 0; n < 4; ++n) {
      int gcol = col0 + wn * 64 + n * 16 + l15;
      float bv = bias[gcol];
#pragma unroll
      for (int r2 = 0; r2 < 4; ++r2) {
        float v = acc[m][n][r2] + bv;
        if constexpr (sizeof(CT) == 2) C[(size_t)(grow + r2) * N + gcol] = (CT)f2bf(v);
        else                           C[(size_t)(grow + r2) * N + gcol] = v;
      }
    }
  }
}

// ---------------- RoPE + split + layout (qkv bf16) ----------------
__global__ __launch_bounds__(256) void k_rope_split(const u16* __restrict__ qkv,
                                                    const float* __restrict__ cosb,
                                                    const float* __restrict__ sinb,
                                                    u16* __restrict__ Qb, u16* __restrict__ Kb,
                                                    u16* __restrict__ Vt) {
  const int bs = blockIdx.x;
  const int b = bs >> 11, s = bs & 2047;
  const size_t base = (size_t)bs * NQKV_;
  const size_t cs = (size_t)bs * D_;
  const float qscale = 0.08838834764831845f;  // 1/sqrt(128)
  for (int p = threadIdx.x; p < H_ * 64; p += 256) {
    int h = p >> 6, d = p & 63;
    float f1 = bf2f(qkv[base + h * D_ + d]);
    float f2 = bf2f(qkv[base + h * D_ + 64 + d]);
    float c1 = cosb[cs + d], s1 = sinb[cs + d];
    float c2 = cosb[cs + 64 + d], s2 = sinb[cs + 64 + d];
    size_t o = ((size_t)(b * H_ + h) * S_ + s) * D_ + d;
    Qb[o] = f2bf((f1 * c1 - f2 * s1) * qscale);
    Qb[o + 64] = f2bf((f2 * c2 + f1 * s2) * qscale);
  }
  for (int p = threadIdx.x; p < HK_ * 64; p += 256) {
    int hk = p >> 6, d = p & 63;
    float f1 = bf2f(qkv[base + H_ * D_ + hk * D_ + d]);
    float f2 = bf2f(qkv[base + H_ * D_ + hk * D_ + 64 + d]);
    float c1 = cosb[cs + d], s1 = sinb[cs + d];
    float c2 = cosb[cs + 64 + d], s2 = sinb[cs + 64 + d];
    size_t o = ((size_t)(b * HK_ + hk) * S_ + s) * D_ + d;
    Kb[o] = f2bf(f1 * c1 - f2 * s1);
    Kb[o + 64] = f2bf(f2 * c2 + f1 * s2);
  }
  for (int p = threadIdx.x; p < HK_ * D_; p += 256) {
    int hk = p >> 7, d = p & 127;
    Vt[((size_t)(b * HK_ + hk) * D_ + d) * S_ + s] = qkv[base + H_ * D_ + HK_ * D_ + hk * D_ + d];
  }
}

// ---------------- flash attention: 4 waves x 32 q-rows (q-tile 128), 32x32 MFMA,
//                  swapped QK^T, in-register softmax, O^T = V^T . P^T
//                  launch_bounds(256,3): cap 170 VGPR -> no spill (R5: (256,4) spilled) ----
__global__ __launch_bounds__(256, 3) void k_attn(const u16* __restrict__ Qb, const u16* __restrict__ Kb,
                                                 const u16* __restrict__ Vt, u16* __restrict__ Ob) {
  __shared__ __attribute__((aligned(16))) char lds[32768];
  char* lKc = lds;            // K tile [64 key][128 d] bf16, XOR (row&15)<<4
  char* lVc = lds + 16384;    // V^T tile [128 d][64 key] bf16, XOR (row&7)<<4
  const int qt = blockIdx.x;  // 0..15
  const int bh = blockIdx.y;  // 0..31
  const int b = bh >> 4, h = bh & 15, hk = h >> 2;
  const int tid = threadIdx.x, lane = tid & 63, wid = tid >> 6;
  const int l31 = lane & 31, hi = lane >> 5;

  const int qrow = qt * 128 + wid * 32 + l31;
  const u16* qptr = Qb + ((size_t)(b * H_ + h) * S_ + qrow) * D_;
  bf16x8 qf[8];
#pragma unroll
  for (int ks = 0; ks < 8; ++ks) qf[ks] = *(const bf16x8*)(qptr + ks * 16 + hi * 8);

  const u16* kbase = Kb + (size_t)(b * HK_ + hk) * S_ * D_;
  const u16* vbase = Vt + (size_t)(b * HK_ + hk) * D_ * S_;

  // staging: 256 threads x 4 slots of 16B each for K (16KB) and V^T (16KB)
  int krow[4], kc[4], vrow[4], vc[4];
#pragma unroll
  for (int i = 0; i < 4; ++i) {
    int s = tid + i * 256;
    krow[i] = s >> 4; kc[i] = s & 15;
    vrow[i] = s >> 3; vc[i] = s & 7;
  }

  f32x16 o[4] = {};
  float mrun = -1e30f, lrun = 0.f;

  bf16x8 kreg[4], vreg[4];
#pragma unroll
  for (int i = 0; i < 4; ++i) {
    kreg[i] = *(const bf16x8*)(kbase + (size_t)krow[i] * D_ + kc[i] * 8);
    vreg[i] = *(const bf16x8*)(vbase + (size_t)vrow[i] * S_ + vc[i] * 8);
  }
#pragma unroll
  for (int i = 0; i < 4; ++i) {
    *(bf16x8*)(lKc + ((krow[i] * 256 + kc[i] * 16) ^ ((krow[i] & 15) << 4))) = kreg[i];
    *(bf16x8*)(lVc + ((vrow[i] * 128 + vc[i] * 16) ^ ((vrow[i] & 7) << 4))) = vreg[i];
  }
  __syncthreads();

  for (int kt = 0; kt < 32; ++kt) {
    // T14: issue next tile's global loads early; write to LDS after the barrier
    if (kt < 31) {
#pragma unroll
      for (int i = 0; i < 4; ++i) {
        kreg[i] = *(const bf16x8*)(kbase + (size_t)((kt + 1) * 64 + krow[i]) * D_ + kc[i] * 8);
        vreg[i] = *(const bf16x8*)(vbase + (size_t)vrow[i] * S_ + (kt + 1) * 64 + vc[i] * 8);
      }
    }

    f32x16 sc[2] = {};
    __builtin_amdgcn_s_setprio(1);
#pragma unroll
    for (int ks = 0; ks < 8; ++ks) {
#pragma unroll
      for (int T = 0; T < 2; ++T) {
        int row = T * 32 + l31;
        bf16x8 kf = *(const bf16x8*)(lKc + ((row * 256 + ks * 32 + hi * 16) ^ ((row & 15) << 4)));
        sc[T] = __builtin_amdgcn_mfma_f32_32x32x16_bf16(kf, qf[ks], sc[T], 0, 0, 0);
      }
    }
    __builtin_amdgcn_s_setprio(0);

    float pmax = sc[0][0];
#pragma unroll
    for (int r = 1; r < 16; ++r) pmax = fmaxf(pmax, sc[0][r]);
#pragma unroll
    for (int r = 0; r < 16; ++r) pmax = fmaxf(pmax, sc[1][r]);
    pmax = fmaxf(pmax, __shfl_xor(pmax, 32));
    if (__any(pmax > mrun + 8.f)) {   // T13 defer-max
      float mn = fmaxf(mrun, pmax);
      float alpha = __expf(mrun - mn);
      mrun = mn;
      lrun *= alpha;
#pragma unroll
      for (int dt = 0; dt < 4; ++dt)
#pragma unroll
        for (int r = 0; r < 16; ++r) o[dt][r] *= alpha;
    }
    float rs = 0.f;
#pragma unroll
    for (int T = 0; T < 2; ++T)
#pragma unroll
      for (int r = 0; r < 16; ++r) {
        float p = __expf(sc[T][r] - mrun);
        sc[T][r] = p;
        rs += p;
      }
    rs += __shfl_xor(rs, 32);
    lrun += rs;

    bf16x8 pf[4];
#pragma unroll
    for (int T = 0; T < 2; ++T) {
#pragma unroll
      for (int g = 0; g < 2; ++g) {
        u32 a0 = cvtpk(sc[T][8 * g + 0], sc[T][8 * g + 1]);
        u32 a1 = cvtpk(sc[T][8 * g + 2], sc[T][8 * g + 3]);
        u32 a2 = cvtpk(sc[T][8 * g + 4], sc[T][8 * g + 5]);
        u32 a3 = cvtpk(sc[T][8 * g + 6], sc[T][8 * g + 7]);
        u32 x0 = (u32)__shfl_xor((int)a0, 32);
        u32 x1 = (u32)__shfl_xor((int)a1, 32);
        u32 x2 = (u32)__shfl_xor((int)a2, 32);
        u32 x3 = (u32)__shfl_xor((int)a3, 32);
        u32 s0 = hi ? x2 : a0;
        u32 s1 = hi ? x3 : a1;
        u32 s2 = hi ? a2 : x0;
        u32 s3 = hi ? a3 : x1;
        u32x4 w = {s0, s1, s2, s3};
        pf[T * 2 + g] = __builtin_bit_cast(bf16x8, w);
      }
    }

    __builtin_amdgcn_s_setprio(1);
#pragma unroll
    for (int ks2 = 0; ks2 < 4; ++ks2) {
#pragma unroll
      for (int dt = 0; dt < 4; ++dt) {
        int row = dt * 32 + l31;
        bf16x8 vf = *(const bf16x8*)(lVc + ((row * 128 + ks2 * 32 + hi * 16) ^ ((row & 7) << 4)));
        o[dt] = __builtin_amdgcn_mfma_f32_32x32x16_bf16(vf, pf[ks2], o[dt], 0, 0, 0);
      }
    }
    __builtin_amdgcn_s_setprio(0);

    __syncthreads();
    if (kt < 31) {
#pragma unroll
      for (int i = 0; i < 4; ++i) {
        *(bf16x8*)(lKc + ((krow[i] * 256 + kc[i] * 16) ^ ((krow[i] & 15) << 4))) = kreg[i];
        *(bf16x8*)(lVc + ((vrow[i] * 128 + vc[i] * 16) ^ ((vrow[i] & 7) << 4))) = vreg[i];
      }
    }
    __syncthreads();
  }

  // epilogue: O^T -> O via per-wave LDS region (8KB each, reuses K/V space)
  float inv = 1.0f / lrun;
  char* myreg = lds + wid * 8192;  // [32 q][128 d] bf16, XOR (q&15)<<4 on byte-in-row
#pragma unroll
  for (int dt = 0; dt < 4; ++dt)
#pragma unroll
    for (int t = 0; t < 8; ++t) {
      u32 w = cvtpk(o[dt][2 * t] * inv, o[dt][2 * t + 1] * inv);
      int d0 = dt * 32 + 2 * (t & 1) + 8 * (t >> 1) + 4 * hi;
      *(u32*)(myreg + ((l31 * 256 + d0 * 2) ^ ((l31 & 15) << 4))) = w;
    }
  asm volatile("s_waitcnt lgkmcnt(0)");
  {
    int q = lane >> 1, hf = lane & 1;
    int srow = qt * 128 + wid * 32 + q;
    u16* orow = Ob + ((size_t)(b * S_ + srow)) * HID_ + h * 128 + hf * 64;
#pragma unroll
    for (int i = 0; i < 8; ++i) {
      bf16x8 vv = *(const bf16x8*)(myreg + ((q * 256 + hf * 128 + i * 16) ^ ((q & 15) << 4)));
      *(bf16x8*)(orow + i * 8) = vv;
    }
  }
}

extern "C" void kernel_launch(void* const* d_in, const int* in_sizes, int n_in,
                              void* d_out, int out_size, void* d_ws, size_t ws_size,
                              hipStream_t stream) {
  const float* hs = (const float*)d_in[0];
  const float* cosb = (const float*)d_in[1];
  const float* sinb = (const float*)d_in[2];
  const float* w_qkv = (const float*)d_in[3];
  const float* b_qkv = (const float*)d_in[4];
  const float* w_o = (const float*)d_in[5];
  const float* b_o = (const float*)d_in[6];
  float* out = (float*)d_out;

  char* ws = (char*)d_ws;
  u16* Xb    = (u16*)ws;                          // 16,777,216 B (reused as attn_out)
  u16* Wqkvb = (u16*)(ws + 16777216);             // 12,582,912 B
  u16* Wob   = (u16*)(ws + 29360128);             //  8,388,608 B
  u16* qkvb  = (u16*)(ws + 37748736);             // 25,165,824 B (bf16)
  u16* Qb    = (u16*)(ws + 62914560);             // 16,777,216 B
  u16* Kb    = (u16*)(ws + 79691776);             //  4,194,304 B
  u16* Vt    = (u16*)(ws + 83886080);             //  4,194,304 B  (total 88,080,384 B)
  u16* Ob = Xb;

  hipLaunchKernelGGL(k_f32_to_bf16, dim3(2048), dim3(256), 0, stream, hs, Xb, (B_ * S_ * HID_) / 8);
  hipLaunchKernelGGL(k_f32_to_bf16, dim3(1536), dim3(256), 0, stream, w_qkv, Wqkvb, (NQKV_ * HID_) / 8);
  hipLaunchKernelGGL(k_f32_to_bf16, dim3(1024), dim3(256), 0, stream, w_o, Wob, (HID_ * HID_) / 8);
  hipLaunchKernelGGL((k_gemm8p<256, u16>), dim3(NQKV_ / 256, (B_ * S_) / 256), dim3(512), 0, stream,
                     Xb, Wqkvb, b_qkv, qkvb, B_ * S_, NQKV_, HID_);
  hipLaunchKernelGGL(k_rope_split, dim3(B_ * S_), dim3(256), 0, stream, qkvb, cosb, sinb, Qb, Kb, Vt);
  hipLaunchKernelGGL(k_attn, dim3(S_ / 128, B_ * H_), dim3(256), 0, stream, Qb, Kb, Vt, Ob);
  hipLaunchKernelGGL((k_gemm8p<128, float>), dim3(HID_ / 256, (B_ * S_) / 128), dim3(512), 0, stream,
                     Ob, Wob, b_o, out, B_ * S_, HID_, HID_);
}

// Round 7
// 219.672 us; speedup vs baseline: 3.0703x; 2.4874x over previous
//
#include <hip/hip_runtime.h>
#include <hip/hip_bf16.h>
#include <stdint.h>

typedef __bf16 bf16x8 __attribute__((ext_vector_type(8)));
typedef float f32x4 __attribute__((ext_vector_type(4)));
typedef float f32x16 __attribute__((ext_vector_type(16)));
typedef float f32x4v __attribute__((ext_vector_type(4)));
typedef unsigned short u16;
typedef unsigned int u32;
typedef u16 u16x8 __attribute__((ext_vector_type(8)));
typedef u32 u32x4 __attribute__((ext_vector_type(4)));

#define B_ 2
#define S_ 2048
#define HID_ 2048
#define H_ 16
#define HK_ 4
#define D_ 128
#define NQKV_ 3072

__device__ __forceinline__ u16 f2bf(float f) {
  u32 u = __builtin_bit_cast(u32, f);
  u32 r = (u + 0x7fffu + ((u >> 16) & 1u)) >> 16;
  return (u16)r;
}
__device__ __forceinline__ float bf2f(u16 v) {
  u32 u = ((u32)v) << 16;
  return __builtin_bit_cast(float, u);
}
__device__ __forceinline__ u32 cvtpk(float lo, float hi) {
  u32 r;
  asm("v_cvt_pk_bf16_f32 %0, %1, %2" : "=v"(r) : "v"(lo), "v"(hi));
  return r;
}
__device__ __forceinline__ void gload_lds16(const void* g, void* l) {
  __builtin_amdgcn_global_load_lds((const __attribute__((address_space(1))) void*)g,
                                   (__attribute__((address_space(3))) void*)l, 16, 0, 0);
}

// ---------------- fused f32 -> bf16 convert for 3 buffers ----------------
__global__ __launch_bounds__(256) void k_cvt3(const float* __restrict__ a, u16* __restrict__ oa, int na,
                                              const float* __restrict__ b, u16* __restrict__ ob, int nb,
                                              const float* __restrict__ c, u16* __restrict__ oc, int nc) {
  int total = na + nb + nc;
  for (int i = blockIdx.x * 256 + threadIdx.x; i < total; i += gridDim.x * 256) {
    const float* src;
    u16* dst;
    int j = i;
    if (j < na) { src = a; dst = oa; }
    else if (j < na + nb) { j -= na; src = b; dst = ob; }
    else { j -= na + nb; src = c; dst = oc; }
    const f32x4v* p = (const f32x4v*)(src + (size_t)j * 8);
    f32x4v x = p[0], y = p[1];
    u16x8 w;
    w[0] = f2bf(x[0]); w[1] = f2bf(x[1]); w[2] = f2bf(x[2]); w[3] = f2bf(x[3]);
    w[4] = f2bf(y[0]); w[5] = f2bf(y[1]); w[6] = f2bf(y[2]); w[7] = f2bf(y[3]);
    *(u16x8*)(dst + (size_t)j * 8) = w;
  }
}

// ---------------- 8-phase deep-pipelined GEMM: C = A[M][K] . B[N][K]^T + bias ----
template <int ISSUES>
__device__ __forceinline__ void stage_half(const u16* __restrict__ src, int K, char* ldsb, int tid) {
#pragma unroll
  for (int i = 0; i < ISSUES; ++i) {
    int off = i * 8192 + tid * 16;
    int r = off >> 7, cb = off & 127;
    int scb = cb ^ ((r & 7) << 4);
    gload_lds16((const char*)(src + (size_t)r * K) + scb, ldsb + i * 8192 + (tid & ~63) * 16);
  }
}

template <int BM, typename CT>
__global__ __launch_bounds__(512, 1) void k_gemm8p(const u16* __restrict__ A, const u16* __restrict__ Bm,
                                                   const float* __restrict__ bias, CT* __restrict__ C,
                                                   int M, int N, int K) {
  constexpr int HAR = BM / 2;            // rows per A half-tile
  constexpr int AHB = HAR * 128;         // bytes per A half-tile
  constexpr int AISS = AHB / 8192;       // gload issues per A half
  constexpr int MREP = BM / 32;          // 16-row frags per wave
  constexpr int MQ = MREP / 4;           // m-frags per phase
  constexpr int DB = 2 * AHB + 32768;    // dbuf stride
  __shared__ __attribute__((aligned(16))) char lds[2 * DB];
  const int tid = threadIdx.x, lane = tid & 63;
  const int wid = tid >> 6, wm = wid >> 2, wn = wid & 3;
  const int l15 = lane & 15, l4 = lane >> 4;
  const int row0 = blockIdx.y * BM, col0 = blockIdx.x * 256;
  const int NT = K >> 6;

  f32x4 acc[MREP][4] = {};

  auto stageA = [&](int t, int h) {
    stage_half<AISS>(A + (size_t)(row0 + h * HAR) * K + t * 64, K, lds + (t & 1) * DB + h * AHB, tid);
  };
  auto stageB = [&](int t, int h) {
    stage_half<2>(Bm + (size_t)(col0 + h * 128) * K + t * 64, K, lds + (t & 1) * DB + 2 * AHB + h * 16384, tid);
  };

  stageA(0, 0); stageA(0, 1); stageB(0, 0); stageB(0, 1);
  if (NT > 1) { stageB(1, 0); stageB(1, 1); }
  if (NT > 1) asm volatile("s_waitcnt vmcnt(4)" ::: "memory");
  else        asm volatile("s_waitcnt vmcnt(0)" ::: "memory");
  __builtin_amdgcn_s_barrier();

  const char* myA = lds + wm * AHB;
  const char* myB = lds + 2 * AHB + (wn >> 1) * 16384;
  const int rBb = (wn & 1) * 64;

  for (int t = 0; t < NT; ++t) {
    const int d = t & 1;
    const char* Ab = myA + d * DB;
    const char* Bb = myB + d * DB;
    bf16x8 bfr[4][2];
#pragma unroll
    for (int j = 0; j < 4; ++j) {
      if (j == 0) {
#pragma unroll
        for (int n = 0; n < 4; ++n)
#pragma unroll
          for (int ks = 0; ks < 2; ++ks) {
            int r = rBb + n * 16 + l15;
            bfr[n][ks] = *(const bf16x8*)(Bb + r * 128 + ((ks * 64 + l4 * 16) ^ ((r & 7) << 4)));
          }
      }
      bf16x8 afr[MQ][2];
#pragma unroll
      for (int mq = 0; mq < MQ; ++mq)
#pragma unroll
        for (int ks = 0; ks < 2; ++ks) {
          int r = (j * MQ + mq) * 16 + l15;
          afr[mq][ks] = *(const bf16x8*)(Ab + r * 128 + ((ks * 64 + l4 * 16) ^ ((r & 7) << 4)));
        }
      if (j == 0) { if (t + 1 < NT) stageA(t + 1, 0); }
      else if (j == 1) { if (t + 1 < NT) stageA(t + 1, 1); }
      else if (j == 2) { if (t + 2 < NT) stageB(t + 2, 0); }
      else {
        if (t + 2 < NT) { stageB(t + 2, 1); asm volatile("s_waitcnt vmcnt(4)" ::: "memory"); }
        else             asm volatile("s_waitcnt vmcnt(0)" ::: "memory");
      }
      __builtin_amdgcn_s_barrier();
      asm volatile("s_waitcnt lgkmcnt(0)" ::: "memory");
      __builtin_amdgcn_s_setprio(1);
#pragma unroll
      for (int mq = 0; mq < MQ; ++mq)
#pragma unroll
        for (int ks = 0; ks < 2; ++ks)
#pragma unroll
          for (int n = 0; n < 4; ++n)
            acc[j * MQ + mq][n] =
                __builtin_amdgcn_mfma_f32_16x16x32_bf16(afr[mq][ks], bfr[n][ks], acc[j * MQ + mq][n], 0, 0, 0);
      __builtin_amdgcn_s_setprio(0);
      __builtin_amdgcn_s_barrier();
    }
  }

#pragma unroll
  for (int m = 0; m < MREP; ++m) {
    int grow = row0 + wm * HAR + m * 16 + l4 * 4;
#pragma unroll
    for (int n = 0; n < 4; ++n) {
      int gcol = col0 + wn * 64 + n * 16 + l15;
      float bv = bias[gcol];
#pragma unroll
      for (int r2 = 0; r2 < 4; ++r2) {
        float v = acc[m][n][r2] + bv;
        if constexpr (sizeof(CT) == 2) C[(size_t)(grow + r2) * N + gcol] = (CT)f2bf(v);
        else                           C[(size_t)(grow + r2) * N + gcol] = v;
      }
    }
  }
}

// ---------------- RoPE + split + layout (qkv bf16) ----------------
__global__ __launch_bounds__(256) void k_rope_split(const u16* __restrict__ qkv,
                                                    const float* __restrict__ cosb,
                                                    const float* __restrict__ sinb,
                                                    u16* __restrict__ Qb, u16* __restrict__ Kb,
                                                    u16* __restrict__ Vt) {
  const int bs = blockIdx.x;
  const int b = bs >> 11, s = bs & 2047;
  const size_t base = (size_t)bs * NQKV_;
  const size_t cs = (size_t)bs * D_;
  const float qscale = 0.08838834764831845f;  // 1/sqrt(128)
  for (int p = threadIdx.x; p < H_ * 64; p += 256) {
    int h = p >> 6, d = p & 63;
    float f1 = bf2f(qkv[base + h * D_ + d]);
    float f2 = bf2f(qkv[base + h * D_ + 64 + d]);
    float c1 = cosb[cs + d], s1 = sinb[cs + d];
    float c2 = cosb[cs + 64 + d], s2 = sinb[cs + 64 + d];
    size_t o = ((size_t)(b * H_ + h) * S_ + s) * D_ + d;
    Qb[o] = f2bf((f1 * c1 - f2 * s1) * qscale);
    Qb[o + 64] = f2bf((f2 * c2 + f1 * s2) * qscale);
  }
  for (int p = threadIdx.x; p < HK_ * 64; p += 256) {
    int hk = p >> 6, d = p & 63;
    float f1 = bf2f(qkv[base + H_ * D_ + hk * D_ + d]);
    float f2 = bf2f(qkv[base + H_ * D_ + hk * D_ + 64 + d]);
    float c1 = cosb[cs + d], s1 = sinb[cs + d];
    float c2 = cosb[cs + 64 + d], s2 = sinb[cs + 64 + d];
    size_t o = ((size_t)(b * HK_ + hk) * S_ + s) * D_ + d;
    Kb[o] = f2bf(f1 * c1 - f2 * s1);
    Kb[o + 64] = f2bf(f2 * c2 + f1 * s2);
  }
  for (int p = threadIdx.x; p < HK_ * D_; p += 256) {
    int hk = p >> 7, d = p & 127;
    Vt[((size_t)(b * HK_ + hk) * D_ + d) * S_ + s] = qkv[base + H_ * D_ + HK_ * D_ + hk * D_ + d];
  }
}

// ---------------- flash attention: 8 waves x 32 q-rows, 32x32 MFMA, swapped QK^T,
//                  in-register softmax, O^T = V^T . P^T, LDS double-buffer
//                  (one barrier per kv-tile) ----------------
__global__ __launch_bounds__(512, 2) void k_attn(const u16* __restrict__ Qb, const u16* __restrict__ Kb,
                                                 const u16* __restrict__ Vt, u16* __restrict__ Ob) {
  __shared__ __attribute__((aligned(16))) char lds[65536];
  // buf d: K tile at d*32768 ([64 key][128 d] bf16, XOR (row&15)<<4),
  //        V^T tile at d*32768+16384 ([128 d][64 key] bf16, XOR (row&7)<<4)
  const int qt = blockIdx.x;  // 0..7
  const int bh = blockIdx.y;  // 0..31
  const int b = bh >> 4, h = bh & 15, hk = h >> 2;
  const int tid = threadIdx.x, lane = tid & 63, wid = tid >> 6;
  const int l31 = lane & 31, hi = lane >> 5;

  const int qrow = qt * 256 + wid * 32 + l31;
  const u16* qptr = Qb + ((size_t)(b * H_ + h) * S_ + qrow) * D_;
  bf16x8 qf[8];
#pragma unroll
  for (int ks = 0; ks < 8; ++ks) qf[ks] = *(const bf16x8*)(qptr + ks * 16 + hi * 8);

  const u16* kbase = Kb + (size_t)(b * HK_ + hk) * S_ * D_;
  const u16* vbase = Vt + (size_t)(b * HK_ + hk) * D_ * S_;

  int krow[2], kc[2], vrow[2], vc[2];
#pragma unroll
  for (int i = 0; i < 2; ++i) {
    int s = tid + i * 512;
    krow[i] = s >> 4; kc[i] = s & 15;
    vrow[i] = s >> 3; vc[i] = s & 7;
  }

  f32x16 o[4] = {};
  float mrun = -1e30f, lrun = 0.f;

  bf16x8 kreg[2], vreg[2];
#pragma unroll
  for (int i = 0; i < 2; ++i) {
    kreg[i] = *(const bf16x8*)(kbase + (size_t)krow[i] * D_ + kc[i] * 8);
    vreg[i] = *(const bf16x8*)(vbase + (size_t)vrow[i] * S_ + vc[i] * 8);
  }
#pragma unroll
  for (int i = 0; i < 2; ++i) {
    *(bf16x8*)(lds + ((krow[i] * 256 + kc[i] * 16) ^ ((krow[i] & 15) << 4))) = kreg[i];
    *(bf16x8*)(lds + 16384 + ((vrow[i] * 128 + vc[i] * 16) ^ ((vrow[i] & 7) << 4))) = vreg[i];
  }
  __syncthreads();

  for (int kt = 0; kt < 32; ++kt) {
    const int cur = kt & 1;
    const char* lKc = lds + cur * 32768;
    const char* lVc = lKc + 16384;

    // T14: issue next tile's global loads early; LDS-write to the OTHER buffer later
    if (kt < 31) {
#pragma unroll
      for (int i = 0; i < 2; ++i) {
        kreg[i] = *(const bf16x8*)(kbase + (size_t)((kt + 1) * 64 + krow[i]) * D_ + kc[i] * 8);
        vreg[i] = *(const bf16x8*)(vbase + (size_t)vrow[i] * S_ + (kt + 1) * 64 + vc[i] * 8);
      }
    }

    f32x16 sc[2] = {};
    __builtin_amdgcn_s_setprio(1);
#pragma unroll
    for (int ks = 0; ks < 8; ++ks) {
#pragma unroll
      for (int T = 0; T < 2; ++T) {
        int row = T * 32 + l31;
        bf16x8 kf = *(const bf16x8*)(lKc + ((row * 256 + ks * 32 + hi * 16) ^ ((row & 15) << 4)));
        sc[T] = __builtin_amdgcn_mfma_f32_32x32x16_bf16(kf, qf[ks], sc[T], 0, 0, 0);
      }
    }
    __builtin_amdgcn_s_setprio(0);

    float pmax = sc[0][0];
#pragma unroll
    for (int r = 1; r < 16; ++r) pmax = fmaxf(pmax, sc[0][r]);
#pragma unroll
    for (int r = 0; r < 16; ++r) pmax = fmaxf(pmax, sc[1][r]);
    pmax = fmaxf(pmax, __shfl_xor(pmax, 32));
    if (__any(pmax > mrun + 8.f)) {   // T13 defer-max
      float mn = fmaxf(mrun, pmax);
      float alpha = __expf(mrun - mn);
      mrun = mn;
      lrun *= alpha;
#pragma unroll
      for (int dt = 0; dt < 4; ++dt)
#pragma unroll
        for (int r = 0; r < 16; ++r) o[dt][r] *= alpha;
    }
    float rs = 0.f;
#pragma unroll
    for (int T = 0; T < 2; ++T)
#pragma unroll
      for (int r = 0; r < 16; ++r) {
        float p = __expf(sc[T][r] - mrun);
        sc[T][r] = p;
        rs += p;
      }
    rs += __shfl_xor(rs, 32);
    lrun += rs;

    bf16x8 pf[4];
#pragma unroll
    for (int T = 0; T < 2; ++T) {
#pragma unroll
      for (int g = 0; g < 2; ++g) {
        u32 a0 = cvtpk(sc[T][8 * g + 0], sc[T][8 * g + 1]);
        u32 a1 = cvtpk(sc[T][8 * g + 2], sc[T][8 * g + 3]);
        u32 a2 = cvtpk(sc[T][8 * g + 4], sc[T][8 * g + 5]);
        u32 a3 = cvtpk(sc[T][8 * g + 6], sc[T][8 * g + 7]);
        u32 x0 = (u32)__shfl_xor((int)a0, 32);
        u32 x1 = (u32)__shfl_xor((int)a1, 32);
        u32 x2 = (u32)__shfl_xor((int)a2, 32);
        u32 x3 = (u32)__shfl_xor((int)a3, 32);
        u32 s0 = hi ? x2 : a0;
        u32 s1 = hi ? x3 : a1;
        u32 s2 = hi ? a2 : x0;
        u32 s3 = hi ? a3 : x1;
        u32x4 w = {s0, s1, s2, s3};
        pf[T * 2 + g] = __builtin_bit_cast(bf16x8, w);
      }
    }

    __builtin_amdgcn_s_setprio(1);
#pragma unroll
    for (int ks2 = 0; ks2 < 4; ++ks2) {
#pragma unroll
      for (int dt = 0; dt < 4; ++dt) {
        int row = dt * 32 + l31;
        bf16x8 vf = *(const bf16x8*)(lVc + ((row * 128 + ks2 * 32 + hi * 16) ^ ((row & 7) << 4)));
        o[dt] = __builtin_amdgcn_mfma_f32_32x32x16_bf16(vf, pf[ks2], o[dt], 0, 0, 0);
      }
    }
    __builtin_amdgcn_s_setprio(0);

    // write next tile into the other buffer (no second barrier needed: disjoint buf)
    if (kt < 31) {
      char* nK = lds + (cur ^ 1) * 32768;
      char* nV = nK + 16384;
#pragma unroll
      for (int i = 0; i < 2; ++i) {
        *(bf16x8*)(nK + ((krow[i] * 256 + kc[i] * 16) ^ ((krow[i] & 15) << 4))) = kreg[i];
        *(bf16x8*)(nV + ((vrow[i] * 128 + vc[i] * 16) ^ ((vrow[i] & 7) << 4))) = vreg[i];
      }
    }
    __syncthreads();
  }

  // epilogue: O^T -> O via per-wave LDS region (8KB each), then coalesced stores
  float inv = 1.0f / lrun;
  char* myreg = lds + wid * 8192;  // [32 q][128 d] bf16, XOR (q&15)<<4 on byte-in-row
#pragma unroll
  for (int dt = 0; dt < 4; ++dt)
#pragma unroll
    for (int t = 0; t < 8; ++t) {
      u32 w = cvtpk(o[dt][2 * t] * inv, o[dt][2 * t + 1] * inv);
      int d0 = dt * 32 + 2 * (t & 1) + 8 * (t >> 1) + 4 * hi;
      *(u32*)(myreg + ((l31 * 256 + d0 * 2) ^ ((l31 & 15) << 4))) = w;
    }
  asm volatile("s_waitcnt lgkmcnt(0)");
  {
    int q = lane >> 1, hf = lane & 1;
    int srow = qt * 256 + wid * 32 + q;
    u16* orow = Ob + ((size_t)(b * S_ + srow)) * HID_ + h * 128 + hf * 64;
#pragma unroll
    for (int i = 0; i < 8; ++i) {
      bf16x8 vv = *(const bf16x8*)(myreg + ((q * 256 + hf * 128 + i * 16) ^ ((q & 15) << 4)));
      *(bf16x8*)(orow + i * 8) = vv;
    }
  }
}

extern "C" void kernel_launch(void* const* d_in, const int* in_sizes, int n_in,
                              void* d_out, int out_size, void* d_ws, size_t ws_size,
                              hipStream_t stream) {
  const float* hs = (const float*)d_in[0];
  const float* cosb = (const float*)d_in[1];
  const float* sinb = (const float*)d_in[2];
  const float* w_qkv = (const float*)d_in[3];
  const float* b_qkv = (const float*)d_in[4];
  const float* w_o = (const float*)d_in[5];
  const float* b_o = (const float*)d_in[6];
  float* out = (float*)d_out;

  char* ws = (char*)d_ws;
  u16* Xb    = (u16*)ws;                          // 16,777,216 B (reused as attn_out)
  u16* Wqkvb = (u16*)(ws + 16777216);             // 12,582,912 B
  u16* Wob   = (u16*)(ws + 29360128);             //  8,388,608 B
  u16* qkvb  = (u16*)(ws + 37748736);             // 25,165,824 B (bf16)
  u16* Qb    = (u16*)(ws + 62914560);             // 16,777,216 B
  u16* Kb    = (u16*)(ws + 79691776);             //  4,194,304 B
  u16* Vt    = (u16*)(ws + 83886080);             //  4,194,304 B  (total 88,080,384 B)
  u16* Ob = Xb;

  hipLaunchKernelGGL(k_cvt3, dim3(2048), dim3(256), 0, stream,
                     hs, Xb, (B_ * S_ * HID_) / 8,
                     w_qkv, Wqkvb, (NQKV_ * HID_) / 8,
                     w_o, Wob, (HID_ * HID_) / 8);
  hipLaunchKernelGGL((k_gemm8p<256, u16>), dim3(NQKV_ / 256, (B_ * S_) / 256), dim3(512), 0, stream,
                     Xb, Wqkvb, b_qkv, qkvb, B_ * S_, NQKV_, HID_);
  hipLaunchKernelGGL(k_rope_split, dim3(B_ * S_), dim3(256), 0, stream, qkvb, cosb, sinb, Qb, Kb, Vt);
  hipLaunchKernelGGL(k_attn, dim3(S_ / 256, B_ * H_), dim3(512), 0, stream, Qb, Kb, Vt, Ob);
  hipLaunchKernelGGL((k_gemm8p<128, float>), dim3(HID_ / 256, (B_ * S_) / 128), dim3(512), 0, stream,
                     Ob, Wob, b_o, out, B_ * S_, HID_, HID_);
}

// Round 8
// 219.507 us; speedup vs baseline: 3.0726x; 1.0008x over previous
//
#include <hip/hip_runtime.h>
#include <hip/hip_bf16.h>
#include <stdint.h>

typedef __bf16 bf16x8 __attribute__((ext_vector_type(8)));
typedef float f32x4 __attribute__((ext_vector_type(4)));
typedef float f32x16 __attribute__((ext_vector_type(16)));
typedef float f32x4v __attribute__((ext_vector_type(4)));
typedef unsigned short u16;
typedef unsigned int u32;
typedef u16 u16x8 __attribute__((ext_vector_type(8)));
typedef u32 u32x4 __attribute__((ext_vector_type(4)));

#define B_ 2
#define S_ 2048
#define HID_ 2048
#define H_ 16
#define HK_ 4
#define D_ 128
#define NQKV_ 3072

__device__ __forceinline__ u16 f2bf(float f) {
  u32 u = __builtin_bit_cast(u32, f);
  u32 r = (u + 0x7fffu + ((u >> 16) & 1u)) >> 16;
  return (u16)r;
}
__device__ __forceinline__ float bf2f(u16 v) {
  u32 u = ((u32)v) << 16;
  return __builtin_bit_cast(float, u);
}
__device__ __forceinline__ u32 cvtpk(float lo, float hi) {
  u32 r;
  asm("v_cvt_pk_bf16_f32 %0, %1, %2" : "=v"(r) : "v"(lo), "v"(hi));
  return r;
}
__device__ __forceinline__ void gload_lds16(const void* g, void* l) {
  __builtin_amdgcn_global_load_lds((const __attribute__((address_space(1))) void*)g,
                                   (__attribute__((address_space(3))) void*)l, 16, 0, 0);
}

// ---------------- fused f32 -> bf16 convert for 3 buffers ----------------
__global__ __launch_bounds__(256) void k_cvt3(const float* __restrict__ a, u16* __restrict__ oa, int na,
                                              const float* __restrict__ b, u16* __restrict__ ob, int nb,
                                              const float* __restrict__ c, u16* __restrict__ oc, int nc) {
  int total = na + nb + nc;
  for (int i = blockIdx.x * 256 + threadIdx.x; i < total; i += gridDim.x * 256) {
    const float* src;
    u16* dst;
    int j = i;
    if (j < na) { src = a; dst = oa; }
    else if (j < na + nb) { j -= na; src = b; dst = ob; }
    else { j -= na + nb; src = c; dst = oc; }
    const f32x4v* p = (const f32x4v*)(src + (size_t)j * 8);
    f32x4v x = p[0], y = p[1];
    u16x8 w;
    w[0] = f2bf(x[0]); w[1] = f2bf(x[1]); w[2] = f2bf(x[2]); w[3] = f2bf(x[3]);
    w[4] = f2bf(y[0]); w[5] = f2bf(y[1]); w[6] = f2bf(y[2]); w[7] = f2bf(y[3]);
    *(u16x8*)(dst + (size_t)j * 8) = w;
  }
}

// ---------------- 8-phase deep-pipelined GEMM: C = A[M][K] . B[N][K]^T + bias ----
template <int ISSUES>
__device__ __forceinline__ void stage_half(const u16* __restrict__ src, int K, char* ldsb, int tid) {
#pragma unroll
  for (int i = 0; i < ISSUES; ++i) {
    int off = i * 8192 + tid * 16;
    int r = off >> 7, cb = off & 127;
    int scb = cb ^ ((r & 7) << 4);
    gload_lds16((const char*)(src + (size_t)r * K) + scb, ldsb + i * 8192 + (tid & ~63) * 16);
  }
}

template <int BM, typename CT>
__global__ __launch_bounds__(512, 1) void k_gemm8p(const u16* __restrict__ A, const u16* __restrict__ Bm,
                                                   const float* __restrict__ bias, CT* __restrict__ C,
                                                   int M, int N, int K) {
  constexpr int HAR = BM / 2;            // rows per A half-tile
  constexpr int AHB = HAR * 128;         // bytes per A half-tile
  constexpr int AISS = AHB / 8192;       // gload issues per A half
  constexpr int MREP = BM / 32;          // 16-row frags per wave
  constexpr int MQ = MREP / 4;           // m-frags per phase
  constexpr int DB = 2 * AHB + 32768;    // dbuf stride
  __shared__ __attribute__((aligned(16))) char lds[2 * DB];
  const int tid = threadIdx.x, lane = tid & 63;
  const int wid = tid >> 6, wm = wid >> 2, wn = wid & 3;
  const int l15 = lane & 15, l4 = lane >> 4;
  const int row0 = blockIdx.y * BM, col0 = blockIdx.x * 256;
  const int NT = K >> 6;

  f32x4 acc[MREP][4] = {};

  auto stageA = [&](int t, int h) {
    stage_half<AISS>(A + (size_t)(row0 + h * HAR) * K + t * 64, K, lds + (t & 1) * DB + h * AHB, tid);
  };
  auto stageB = [&](int t, int h) {
    stage_half<2>(Bm + (size_t)(col0 + h * 128) * K + t * 64, K, lds + (t & 1) * DB + 2 * AHB + h * 16384, tid);
  };

  stageA(0, 0); stageA(0, 1); stageB(0, 0); stageB(0, 1);
  if (NT > 1) { stageB(1, 0); stageB(1, 1); }
  if (NT > 1) asm volatile("s_waitcnt vmcnt(4)" ::: "memory");
  else        asm volatile("s_waitcnt vmcnt(0)" ::: "memory");
  __builtin_amdgcn_s_barrier();

  const char* myA = lds + wm * AHB;
  const char* myB = lds + 2 * AHB + (wn >> 1) * 16384;
  const int rBb = (wn & 1) * 64;

  for (int t = 0; t < NT; ++t) {
    const int d = t & 1;
    const char* Ab = myA + d * DB;
    const char* Bb = myB + d * DB;
    bf16x8 bfr[4][2];
#pragma unroll
    for (int j = 0; j < 4; ++j) {
      if (j == 0) {
#pragma unroll
        for (int n = 0; n < 4; ++n)
#pragma unroll
          for (int ks = 0; ks < 2; ++ks) {
            int r = rBb + n * 16 + l15;
            bfr[n][ks] = *(const bf16x8*)(Bb + r * 128 + ((ks * 64 + l4 * 16) ^ ((r & 7) << 4)));
          }
      }
      bf16x8 afr[MQ][2];
#pragma unroll
      for (int mq = 0; mq < MQ; ++mq)
#pragma unroll
        for (int ks = 0; ks < 2; ++ks) {
          int r = (j * MQ + mq) * 16 + l15;
          afr[mq][ks] = *(const bf16x8*)(Ab + r * 128 + ((ks * 64 + l4 * 16) ^ ((r & 7) << 4)));
        }
      if (j == 0) { if (t + 1 < NT) stageA(t + 1, 0); }
      else if (j == 1) { if (t + 1 < NT) stageA(t + 1, 1); }
      else if (j == 2) { if (t + 2 < NT) stageB(t + 2, 0); }
      else {
        if (t + 2 < NT) { stageB(t + 2, 1); asm volatile("s_waitcnt vmcnt(4)" ::: "memory"); }
        else             asm volatile("s_waitcnt vmcnt(0)" ::: "memory");
      }
      __builtin_amdgcn_s_barrier();
      asm volatile("s_waitcnt lgkmcnt(0)" ::: "memory");
      __builtin_amdgcn_s_setprio(1);
#pragma unroll
      for (int mq = 0; mq < MQ; ++mq)
#pragma unroll
        for (int ks = 0; ks < 2; ++ks)
#pragma unroll
          for (int n = 0; n < 4; ++n)
            acc[j * MQ + mq][n] =
                __builtin_amdgcn_mfma_f32_16x16x32_bf16(afr[mq][ks], bfr[n][ks], acc[j * MQ + mq][n], 0, 0, 0);
      __builtin_amdgcn_s_setprio(0);
      __builtin_amdgcn_s_barrier();
    }
  }

#pragma unroll
  for (int m = 0; m < MREP; ++m) {
    int grow = row0 + wm * HAR + m * 16 + l4 * 4;
#pragma unroll
    for (int n = 0; n < 4; ++n) {
      int gcol = col0 + wn * 64 + n * 16 + l15;
      float bv = bias[gcol];
#pragma unroll
      for (int r2 = 0; r2 < 4; ++r2) {
        float v = acc[m][n][r2] + bv;
        if constexpr (sizeof(CT) == 2) C[(size_t)(grow + r2) * N + gcol] = (CT)f2bf(v);
        else                           C[(size_t)(grow + r2) * N + gcol] = v;
      }
    }
  }
}

// ---------------- RoPE + split + layout (qkv bf16) ----------------
__global__ __launch_bounds__(256) void k_rope_split(const u16* __restrict__ qkv,
                                                    const float* __restrict__ cosb,
                                                    const float* __restrict__ sinb,
                                                    u16* __restrict__ Qb, u16* __restrict__ Kb,
                                                    u16* __restrict__ Vt) {
  const int bs = blockIdx.x;
  const int b = bs >> 11, s = bs & 2047;
  const size_t base = (size_t)bs * NQKV_;
  const size_t cs = (size_t)bs * D_;
  const float qscale = 0.08838834764831845f;  // 1/sqrt(128)
  for (int p = threadIdx.x; p < H_ * 64; p += 256) {
    int h = p >> 6, d = p & 63;
    float f1 = bf2f(qkv[base + h * D_ + d]);
    float f2 = bf2f(qkv[base + h * D_ + 64 + d]);
    float c1 = cosb[cs + d], s1 = sinb[cs + d];
    float c2 = cosb[cs + 64 + d], s2 = sinb[cs + 64 + d];
    size_t o = ((size_t)(b * H_ + h) * S_ + s) * D_ + d;
    Qb[o] = f2bf((f1 * c1 - f2 * s1) * qscale);
    Qb[o + 64] = f2bf((f2 * c2 + f1 * s2) * qscale);
  }
  for (int p = threadIdx.x; p < HK_ * 64; p += 256) {
    int hk = p >> 6, d = p & 63;
    float f1 = bf2f(qkv[base + H_ * D_ + hk * D_ + d]);
    float f2 = bf2f(qkv[base + H_ * D_ + hk * D_ + 64 + d]);
    float c1 = cosb[cs + d], s1 = sinb[cs + d];
    float c2 = cosb[cs + 64 + d], s2 = sinb[cs + 64 + d];
    size_t o = ((size_t)(b * HK_ + hk) * S_ + s) * D_ + d;
    Kb[o] = f2bf(f1 * c1 - f2 * s1);
    Kb[o + 64] = f2bf(f2 * c2 + f1 * s2);
  }
  for (int p = threadIdx.x; p < HK_ * D_; p += 256) {
    int hk = p >> 7, d = p & 127;
    Vt[((size_t)(b * HK_ + hk) * D_ + d) * S_ + s] = qkv[base + H_ * D_ + HK_ * D_ + hk * D_ + d];
  }
}

// ---------------- flash attention: 8 waves x 32 q-rows, 32x32 MFMA, swapped QK^T,
//                  T15 double-pipeline: QK(t) overlaps softmax+PV of tile t-1 ----------------
__global__ __launch_bounds__(512, 2) void k_attn(const u16* __restrict__ Qb, const u16* __restrict__ Kb,
                                                 const u16* __restrict__ Vt, u16* __restrict__ Ob) {
  __shared__ __attribute__((aligned(16))) char lds[65536];
  // buf d (d = t&1): K tile at d*32768 ([64 key][128 d] bf16, XOR (row&15)<<4),
  //                  V^T tile at d*32768+16384 ([128 d][64 key] bf16, XOR (row&7)<<4)
  const int qt = blockIdx.x;  // 0..7
  const int bh = blockIdx.y;  // 0..31
  const int b = bh >> 4, h = bh & 15, hk = h >> 2;
  const int tid = threadIdx.x, lane = tid & 63, wid = tid >> 6;
  const int l31 = lane & 31, hi = lane >> 5;

  const int qrow = qt * 256 + wid * 32 + l31;
  const u16* qptr = Qb + ((size_t)(b * H_ + h) * S_ + qrow) * D_;
  bf16x8 qf[8];
#pragma unroll
  for (int ks = 0; ks < 8; ++ks) qf[ks] = *(const bf16x8*)(qptr + ks * 16 + hi * 8);

  const u16* kbase = Kb + (size_t)(b * HK_ + hk) * S_ * D_;
  const u16* vbase = Vt + (size_t)(b * HK_ + hk) * D_ * S_;

  int krow[2], kc[2], vrow[2], vc[2];
#pragma unroll
  for (int i = 0; i < 2; ++i) {
    int s = tid + i * 512;
    krow[i] = s >> 4; kc[i] = s & 15;
    vrow[i] = s >> 3; vc[i] = s & 7;
  }

  f32x16 o[4] = {};
  float mrun = -1e30f, lrun = 0.f;

  bf16x8 kreg[2], vreg[2];

  auto stage_load = [&](int t) {   // fetch tile t into kreg/vreg
#pragma unroll
    for (int i = 0; i < 2; ++i) {
      kreg[i] = *(const bf16x8*)(kbase + (size_t)(t * 64 + krow[i]) * D_ + kc[i] * 8);
      vreg[i] = *(const bf16x8*)(vbase + (size_t)vrow[i] * S_ + t * 64 + vc[i] * 8);
    }
  };
  auto stage_write = [&](int t) {  // write kreg/vreg (tile t) into buf[t&1]
    char* nK = lds + (t & 1) * 32768;
    char* nV = nK + 16384;
#pragma unroll
    for (int i = 0; i < 2; ++i) {
      *(bf16x8*)(nK + ((krow[i] * 256 + kc[i] * 16) ^ ((krow[i] & 15) << 4))) = kreg[i];
      *(bf16x8*)(nV + ((vrow[i] * 128 + vc[i] * 16) ^ ((vrow[i] & 7) << 4))) = vreg[i];
    }
  };
  auto qk = [&](const char* lK, f32x16& c0, f32x16& c1) {
    f32x16 zz = {};
    c0 = zz; c1 = zz;
#pragma unroll
    for (int ks = 0; ks < 8; ++ks) {
      int rowa = l31;
      bf16x8 kf0 = *(const bf16x8*)(lK + ((rowa * 256 + ks * 32 + hi * 16) ^ ((rowa & 15) << 4)));
      c0 = __builtin_amdgcn_mfma_f32_32x32x16_bf16(kf0, qf[ks], c0, 0, 0, 0);
      int rowb = 32 + l31;
      bf16x8 kf1 = *(const bf16x8*)(lK + ((rowb * 256 + ks * 32 + hi * 16) ^ ((rowb & 15) << 4)));
      c1 = __builtin_amdgcn_mfma_f32_32x32x16_bf16(kf1, qf[ks], c1, 0, 0, 0);
    }
  };
  auto finish = [&](f32x16& p0, f32x16& p1, const char* lV) {
    float pmax = p0[0];
#pragma unroll
    for (int r = 1; r < 16; ++r) pmax = fmaxf(pmax, p0[r]);
#pragma unroll
    for (int r = 0; r < 16; ++r) pmax = fmaxf(pmax, p1[r]);
    pmax = fmaxf(pmax, __shfl_xor(pmax, 32));
    if (__any(pmax > mrun + 8.f)) {   // T13 defer-max
      float mn = fmaxf(mrun, pmax);
      float alpha = __expf(mrun - mn);
      mrun = mn;
      lrun *= alpha;
#pragma unroll
      for (int dt = 0; dt < 4; ++dt)
#pragma unroll
        for (int r = 0; r < 16; ++r) o[dt][r] *= alpha;
    }
    float rs = 0.f;
#pragma unroll
    for (int r = 0; r < 16; ++r) { float p = __expf(p0[r] - mrun); p0[r] = p; rs += p; }
#pragma unroll
    for (int r = 0; r < 16; ++r) { float p = __expf(p1[r] - mrun); p1[r] = p; rs += p; }
    rs += __shfl_xor(rs, 32);
    lrun += rs;

    bf16x8 pf[4];
#pragma unroll
    for (int g = 0; g < 2; ++g) {
      u32 a0 = cvtpk(p0[8 * g + 0], p0[8 * g + 1]);
      u32 a1 = cvtpk(p0[8 * g + 2], p0[8 * g + 3]);
      u32 a2 = cvtpk(p0[8 * g + 4], p0[8 * g + 5]);
      u32 a3 = cvtpk(p0[8 * g + 6], p0[8 * g + 7]);
      u32 x0 = (u32)__shfl_xor((int)a0, 32);
      u32 x1 = (u32)__shfl_xor((int)a1, 32);
      u32 x2 = (u32)__shfl_xor((int)a2, 32);
      u32 x3 = (u32)__shfl_xor((int)a3, 32);
      u32 s0 = hi ? x2 : a0;
      u32 s1 = hi ? x3 : a1;
      u32 s2 = hi ? a2 : x0;
      u32 s3 = hi ? a3 : x1;
      u32x4 w = {s0, s1, s2, s3};
      pf[g] = __builtin_bit_cast(bf16x8, w);
    }
#pragma unroll
    for (int g = 0; g < 2; ++g) {
      u32 a0 = cvtpk(p1[8 * g + 0], p1[8 * g + 1]);
      u32 a1 = cvtpk(p1[8 * g + 2], p1[8 * g + 3]);
      u32 a2 = cvtpk(p1[8 * g + 4], p1[8 * g + 5]);
      u32 a3 = cvtpk(p1[8 * g + 6], p1[8 * g + 7]);
      u32 x0 = (u32)__shfl_xor((int)a0, 32);
      u32 x1 = (u32)__shfl_xor((int)a1, 32);
      u32 x2 = (u32)__shfl_xor((int)a2, 32);
      u32 x3 = (u32)__shfl_xor((int)a3, 32);
      u32 s0 = hi ? x2 : a0;
      u32 s1 = hi ? x3 : a1;
      u32 s2 = hi ? a2 : x0;
      u32 s3 = hi ? a3 : x1;
      u32x4 w = {s0, s1, s2, s3};
      pf[2 + g] = __builtin_bit_cast(bf16x8, w);
    }

    __builtin_amdgcn_s_setprio(1);
#pragma unroll
    for (int ks2 = 0; ks2 < 4; ++ks2)
#pragma unroll
      for (int dt = 0; dt < 4; ++dt) {
        int row = dt * 32 + l31;
        bf16x8 vf = *(const bf16x8*)(lV + ((row * 128 + ks2 * 32 + hi * 16) ^ ((row & 7) << 4)));
        o[dt] = __builtin_amdgcn_mfma_f32_32x32x16_bf16(vf, pf[ks2], o[dt], 0, 0, 0);
      }
    __builtin_amdgcn_s_setprio(0);
  };

  // ---- prologue: tiles 0,1 into buf0,buf1; QK(0) ----
  f32x16 scA0, scA1, scB0, scB1;
  stage_load(0);
  stage_write(0);          // compiler inserts vmcnt waits on kreg/vreg use
  stage_load(1);
  __syncthreads();         // buf0 ready
  qk(lds, scA0, scA1);     // QK(0) from buf0
  stage_write(1);          // buf1 (disjoint from buf0 reads)
  stage_load(2);
  __syncthreads();         // buf1 ready

  auto iter = [&](int t, f32x16& c0, f32x16& c1, f32x16& p0, f32x16& p1) {
    qk(lds + (t & 1) * 32768, c0, c1);                       // QK(t)    [MFMA]
    finish(p0, p1, lds + ((t & 1) ^ 1) * 32768 + 16384);     // tile t-1 [VALU+MFMA]
    __syncthreads();                                         // buf[(t&1)^1] drained
    if (t < 31) stage_write(t + 1);                          // tile t+1 -> buf[(t+1)&1]
    if (t < 30) stage_load(t + 2);
    __syncthreads();                                         // publish
  };

  iter(1, scB0, scB1, scA0, scA1);
#pragma unroll 1
  for (int i = 0; i < 15; ++i) {
    iter(2 + 2 * i, scA0, scA1, scB0, scB1);
    iter(3 + 2 * i, scB0, scB1, scA0, scA1);
  }
  finish(scB0, scB1, lds + 32768 + 16384);                   // tail: tile 31 (buf1 V)
  __syncthreads();                                           // before epilogue LDS reuse

  // epilogue: O^T -> O via per-wave LDS region (8KB each), then coalesced stores
  float inv = 1.0f / lrun;
  char* myreg = lds + wid * 8192;  // [32 q][128 d] bf16, XOR (q&15)<<4 on byte-in-row
#pragma unroll
  for (int dt = 0; dt < 4; ++dt)
#pragma unroll
    for (int t = 0; t < 8; ++t) {
      u32 w = cvtpk(o[dt][2 * t] * inv, o[dt][2 * t + 1] * inv);
      int d0 = dt * 32 + 2 * (t & 1) + 8 * (t >> 1) + 4 * hi;
      *(u32*)(myreg + ((l31 * 256 + d0 * 2) ^ ((l31 & 15) << 4))) = w;
    }
  asm volatile("s_waitcnt lgkmcnt(0)");
  {
    int q = lane >> 1, hf = lane & 1;
    int srow = qt * 256 + wid * 32 + q;
    u16* orow = Ob + ((size_t)(b * S_ + srow)) * HID_ + h * 128 + hf * 64;
#pragma unroll
    for (int i = 0; i < 8; ++i) {
      bf16x8 vv = *(const bf16x8*)(myreg + ((q * 256 + hf * 128 + i * 16) ^ ((q & 15) << 4)));
      *(bf16x8*)(orow + i * 8) = vv;
    }
  }
}

extern "C" void kernel_launch(void* const* d_in, const int* in_sizes, int n_in,
                              void* d_out, int out_size, void* d_ws, size_t ws_size,
                              hipStream_t stream) {
  const float* hs = (const float*)d_in[0];
  const float* cosb = (const float*)d_in[1];
  const float* sinb = (const float*)d_in[2];
  const float* w_qkv = (const float*)d_in[3];
  const float* b_qkv = (const float*)d_in[4];
  const float* w_o = (const float*)d_in[5];
  const float* b_o = (const float*)d_in[6];
  float* out = (float*)d_out;

  char* ws = (char*)d_ws;
  u16* Xb    = (u16*)ws;                          // 16,777,216 B (reused as attn_out)
  u16* Wqkvb = (u16*)(ws + 16777216);             // 12,582,912 B
  u16* Wob   = (u16*)(ws + 29360128);             //  8,388,608 B
  u16* qkvb  = (u16*)(ws + 37748736);             // 25,165,824 B (bf16)
  u16* Qb    = (u16*)(ws + 62914560);             // 16,777,216 B
  u16* Kb    = (u16*)(ws + 79691776);             //  4,194,304 B
  u16* Vt    = (u16*)(ws + 83886080);             //  4,194,304 B  (total 88,080,384 B)
  u16* Ob = Xb;

  hipLaunchKernelGGL(k_cvt3, dim3(2048), dim3(256), 0, stream,
                     hs, Xb, (B_ * S_ * HID_) / 8,
                     w_qkv, Wqkvb, (NQKV_ * HID_) / 8,
                     w_o, Wob, (HID_ * HID_) / 8);
  hipLaunchKernelGGL((k_gemm8p<256, u16>), dim3(NQKV_ / 256, (B_ * S_) / 256), dim3(512), 0, stream,
                     Xb, Wqkvb, b_qkv, qkvb, B_ * S_, NQKV_, HID_);
  hipLaunchKernelGGL(k_rope_split, dim3(B_ * S_), dim3(256), 0, stream, qkvb, cosb, sinb, Qb, Kb, Vt);
  hipLaunchKernelGGL(k_attn, dim3(S_ / 256, B_ * H_), dim3(512), 0, stream, Qb, Kb, Vt, Ob);
  hipLaunchKernelGGL((k_gemm8p<128, float>), dim3(HID_ / 256, (B_ * S_) / 128), dim3(512), 0, stream,
                     Ob, Wob, b_o, out, B_ * S_, HID_, HID_);
}

// Round 11
// 217.791 us; speedup vs baseline: 3.0968x; 1.0079x over previous
//
#include <hip/hip_runtime.h>
#include <hip/hip_bf16.h>
#include <stdint.h>

typedef __bf16 bf16x8 __attribute__((ext_vector_type(8)));
typedef float f32x4 __attribute__((ext_vector_type(4)));
typedef float f32x16 __attribute__((ext_vector_type(16)));
typedef float f32x4v __attribute__((ext_vector_type(4)));
typedef unsigned short u16;
typedef unsigned int u32;
typedef u16 u16x8 __attribute__((ext_vector_type(8)));
typedef u32 u32x4 __attribute__((ext_vector_type(4)));

#define B_ 2
#define S_ 2048
#define HID_ 2048
#define H_ 16
#define HK_ 4
#define D_ 128
#define NQKV_ 3072

__device__ __forceinline__ u16 f2bf(float f) {
  u32 u = __builtin_bit_cast(u32, f);
  u32 r = (u + 0x7fffu + ((u >> 16) & 1u)) >> 16;
  return (u16)r;
}
__device__ __forceinline__ float bf2f(u16 v) {
  u32 u = ((u32)v) << 16;
  return __builtin_bit_cast(float, u);
}
__device__ __forceinline__ u32 cvtpk(float lo, float hi) {
  u32 r;
  asm("v_cvt_pk_bf16_f32 %0, %1, %2" : "=v"(r) : "v"(lo), "v"(hi));
  return r;
}
__device__ __forceinline__ void gload_lds16(const void* g, void* l) {
  __builtin_amdgcn_global_load_lds((const __attribute__((address_space(1))) void*)g,
                                   (__attribute__((address_space(3))) void*)l, 16, 0, 0);
}

// ---------------- fused f32 -> bf16 convert for 3 buffers ----------------
__global__ __launch_bounds__(256) void k_cvt3(const float* __restrict__ a, u16* __restrict__ oa, int na,
                                              const float* __restrict__ b, u16* __restrict__ ob, int nb,
                                              const float* __restrict__ c, u16* __restrict__ oc, int nc) {
  int total = na + nb + nc;
  for (int i = blockIdx.x * 256 + threadIdx.x; i < total; i += gridDim.x * 256) {
    const float* src;
    u16* dst;
    int j = i;
    if (j < na) { src = a; dst = oa; }
    else if (j < na + nb) { j -= na; src = b; dst = ob; }
    else { j -= na + nb; src = c; dst = oc; }
    const f32x4v* p = (const f32x4v*)(src + (size_t)j * 8);
    f32x4v x = p[0], y = p[1];
    u16x8 w;
    w[0] = f2bf(x[0]); w[1] = f2bf(x[1]); w[2] = f2bf(x[2]); w[3] = f2bf(x[3]);
    w[4] = f2bf(y[0]); w[5] = f2bf(y[1]); w[6] = f2bf(y[2]); w[7] = f2bf(y[3]);
    *(u16x8*)(dst + (size_t)j * 8) = w;
  }
}

// ---------------- 8-phase deep-pipelined GEMM: C = A[M][K] . B[N][K]^T + bias ----
// T1: XCD-aware bijective block swizzle (nwg % 8 == 0 for all launches here).
template <int ISSUES>
__device__ __forceinline__ void stage_half(const u16* __restrict__ src, int K, char* ldsb, int tid) {
#pragma unroll
  for (int i = 0; i < ISSUES; ++i) {
    int off = i * 8192 + tid * 16;
    int r = off >> 7, cb = off & 127;
    int scb = cb ^ ((r & 7) << 4);
    gload_lds16((const char*)(src + (size_t)r * K) + scb, ldsb + i * 8192 + (tid & ~63) * 16);
  }
}

template <int BM, typename CT>
__global__ __launch_bounds__(512, 1) void k_gemm8p(const u16* __restrict__ A, const u16* __restrict__ Bm,
                                                   const float* __restrict__ bias, CT* __restrict__ C,
                                                   int M, int N, int K) {
  constexpr int HAR = BM / 2;            // rows per A half-tile
  constexpr int AHB = HAR * 128;         // bytes per A half-tile
  constexpr int AISS = AHB / 8192;       // gload issues per A half
  constexpr int MREP = BM / 32;          // 16-row frags per wave
  constexpr int MQ = MREP / 4;           // m-frags per phase
  constexpr int DB = 2 * AHB + 32768;    // dbuf stride
  __shared__ __attribute__((aligned(16))) char lds[2 * DB];
  const int tid = threadIdx.x, lane = tid & 63;
  const int wid = tid >> 6, wm = wid >> 2, wn = wid & 3;
  const int l15 = lane & 15, l4 = lane >> 4;
  // T1 swizzle: each XCD gets a contiguous chunk of tile space
  const int nwg = gridDim.x * gridDim.y;
  const int bid = blockIdx.y * gridDim.x + blockIdx.x;
  const int wgid = (bid & 7) * (nwg >> 3) + (bid >> 3);
  const int bx = wgid % gridDim.x, by = wgid / gridDim.x;
  const int row0 = by * BM, col0 = bx * 256;
  const int NT = K >> 6;

  f32x4 acc[MREP][4] = {};

  auto stageA = [&](int t, int h) {
    stage_half<AISS>(A + (size_t)(row0 + h * HAR) * K + t * 64, K, lds + (t & 1) * DB + h * AHB, tid);
  };
  auto stageB = [&](int t, int h) {
    stage_half<2>(Bm + (size_t)(col0 + h * 128) * K + t * 64, K, lds + (t & 1) * DB + 2 * AHB + h * 16384, tid);
  };

  stageA(0, 0); stageA(0, 1); stageB(0, 0); stageB(0, 1);
  if (NT > 1) { stageB(1, 0); stageB(1, 1); }
  if (NT > 1) asm volatile("s_waitcnt vmcnt(4)" ::: "memory");
  else        asm volatile("s_waitcnt vmcnt(0)" ::: "memory");
  __builtin_amdgcn_s_barrier();

  const char* myA = lds + wm * AHB;
  const char* myB = lds + 2 * AHB + (wn >> 1) * 16384;
  const int rBb = (wn & 1) * 64;

  for (int t = 0; t < NT; ++t) {
    const int d = t & 1;
    const char* Ab = myA + d * DB;
    const char* Bb = myB + d * DB;
    bf16x8 bfr[4][2];
#pragma unroll
    for (int j = 0; j < 4; ++j) {
      if (j == 0) {
#pragma unroll
        for (int n = 0; n < 4; ++n)
#pragma unroll
          for (int ks = 0; ks < 2; ++ks) {
            int r = rBb + n * 16 + l15;
            bfr[n][ks] = *(const bf16x8*)(Bb + r * 128 + ((ks * 64 + l4 * 16) ^ ((r & 7) << 4)));
          }
      }
      bf16x8 afr[MQ][2];
#pragma unroll
      for (int mq = 0; mq < MQ; ++mq)
#pragma unroll
        for (int ks = 0; ks < 2; ++ks) {
          int r = (j * MQ + mq) * 16 + l15;
          afr[mq][ks] = *(const bf16x8*)(Ab + r * 128 + ((ks * 64 + l4 * 16) ^ ((r & 7) << 4)));
        }
      if (j == 0) { if (t + 1 < NT) stageA(t + 1, 0); }
      else if (j == 1) { if (t + 1 < NT) stageA(t + 1, 1); }
      else if (j == 2) { if (t + 2 < NT) stageB(t + 2, 0); }
      else {
        if (t + 2 < NT) { stageB(t + 2, 1); asm volatile("s_waitcnt vmcnt(4)" ::: "memory"); }
        else             asm volatile("s_waitcnt vmcnt(0)" ::: "memory");
      }
      __builtin_amdgcn_s_barrier();
      asm volatile("s_waitcnt lgkmcnt(0)" ::: "memory");
      __builtin_amdgcn_s_setprio(1);
#pragma unroll
      for (int mq = 0; mq < MQ; ++mq)
#pragma unroll
        for (int ks = 0; ks < 2; ++ks)
#pragma unroll
          for (int n = 0; n < 4; ++n)
            acc[j * MQ + mq][n] =
                __builtin_amdgcn_mfma_f32_16x16x32_bf16(afr[mq][ks], bfr[n][ks], acc[j * MQ + mq][n], 0, 0, 0);
      __builtin_amdgcn_s_setprio(0);
      __builtin_amdgcn_s_barrier();
    }
  }

#pragma unroll
  for (int m = 0; m < MREP; ++m) {
    int grow = row0 + wm * HAR + m * 16 + l4 * 4;
#pragma unroll
    for (int n = 0; n < 4; ++n) {
      int gcol = col0 + wn * 64 + n * 16 + l15;
      float bv = bias[gcol];
#pragma unroll
      for (int r2 = 0; r2 < 4; ++r2) {
        float v = acc[m][n][r2] + bv;
        if constexpr (sizeof(CT) == 2) C[(size_t)(grow + r2) * N + gcol] = (CT)f2bf(v);
        else                           C[(size_t)(grow + r2) * N + gcol] = v;
      }
    }
  }
}

// ---------------- RoPE + split + layout (qkv bf16), vectorized bf16x8 ----------------
// 256 threads per (b,s): tid 0..127 -> Q (16 heads x 8 chunks), 128..159 -> K,
// 160..223 -> V copy. Each q/k thread processes d0..d0+7 and d0+64..d0+71.
__global__ __launch_bounds__(256) void k_rope_split(const u16* __restrict__ qkv,
                                                    const float* __restrict__ cosb,
                                                    const float* __restrict__ sinb,
                                                    u16* __restrict__ Qb, u16* __restrict__ Kb,
                                                    u16* __restrict__ Vt) {
  const int bs = blockIdx.x;
  const int b = bs >> 11, s = bs & 2047;
  const size_t base = (size_t)bs * NQKV_;
  const size_t cs = (size_t)bs * D_;
  const int tid = threadIdx.x;
  const float qscale = 0.08838834764831845f;  // 1/sqrt(128)

  if (tid < 160) {
    // q: tid<128 -> h = tid>>3; k: tid in [128,160) -> hk = (tid-128)>>3
    const bool isq = tid < 128;
    const int idx = isq ? tid : (tid - 128);
    const int hh = idx >> 3, d0 = (idx & 7) * 8;
    const size_t srcb = base + (isq ? 0 : H_ * D_) + hh * D_;
    bf16x8 x1 = *(const bf16x8*)(qkv + srcb + d0);
    bf16x8 x2 = *(const bf16x8*)(qkv + srcb + d0 + 64);
    u16x8 y1, y2;
    const u16x8 u1 = __builtin_bit_cast(u16x8, x1);
    const u16x8 u2 = __builtin_bit_cast(u16x8, x2);
    const float sc = isq ? qscale : 1.0f;
#pragma unroll
    for (int i = 0; i < 8; ++i) {
      float f1 = bf2f(u1[i]), f2 = bf2f(u2[i]);
      float c1 = cosb[cs + d0 + i], s1 = sinb[cs + d0 + i];
      float c2 = cosb[cs + 64 + d0 + i], s2 = sinb[cs + 64 + d0 + i];
      y1[i] = f2bf((f1 * c1 - f2 * s1) * sc);
      y2[i] = f2bf((f2 * c2 + f1 * s2) * sc);
    }
    size_t o;
    if (isq) o = ((size_t)(b * H_ + hh) * S_ + s) * D_ + d0;
    else     o = ((size_t)(b * HK_ + hh) * S_ + s) * D_ + d0;
    u16* dst = isq ? Qb : Kb;
    *(u16x8*)(dst + o) = y1;
    *(u16x8*)(dst + o + 64) = y2;
  } else if (tid < 224) {
    // v: 64 threads, hk = idx>>4, d0 = (idx&15)*8 ; transposed scatter to Vt[d][s]
    const int idx = tid - 160;
    const int hk = idx >> 4, d0 = (idx & 15) * 8;
    bf16x8 xv = *(const bf16x8*)(qkv + base + (H_ + HK_) * D_ + hk * D_ + d0);
    const u16x8 uv = __builtin_bit_cast(u16x8, xv);
    u16* vb = Vt + (size_t)(b * HK_ + hk) * D_ * S_ + s;
#pragma unroll
    for (int i = 0; i < 8; ++i) vb[(size_t)(d0 + i) * S_] = uv[i];
  }
}

// ---------------- flash attention (R7 known-good): 8 waves x 32 q-rows, 32x32 MFMA,
//                  swapped QK^T, in-register softmax, O^T = V^T . P^T,
//                  LDS double-buffer, one barrier per kv-tile ----------------
__global__ __launch_bounds__(512, 2) void k_attn(const u16* __restrict__ Qb, const u16* __restrict__ Kb,
                                                 const u16* __restrict__ Vt, u16* __restrict__ Ob) {
  __shared__ __attribute__((aligned(16))) char lds[65536];
  const int qt = blockIdx.x;  // 0..7
  const int bh = blockIdx.y;  // 0..31
  const int b = bh >> 4, h = bh & 15, hk = h >> 2;
  const int tid = threadIdx.x, lane = tid & 63, wid = tid >> 6;
  const int l31 = lane & 31, hi = lane >> 5;

  const int qrow = qt * 256 + wid * 32 + l31;
  const u16* qptr = Qb + ((size_t)(b * H_ + h) * S_ + qrow) * D_;
  bf16x8 qf[8];
#pragma unroll
  for (int ks = 0; ks < 8; ++ks) qf[ks] = *(const bf16x8*)(qptr + ks * 16 + hi * 8);

  const u16* kbase = Kb + (size_t)(b * HK_ + hk) * S_ * D_;
  const u16* vbase = Vt + (size_t)(b * HK_ + hk) * D_ * S_;

  int krow[2], kc[2], vrow[2], vc[2];
#pragma unroll
  for (int i = 0; i < 2; ++i) {
    int s = tid + i * 512;
    krow[i] = s >> 4; kc[i] = s & 15;
    vrow[i] = s >> 3; vc[i] = s & 7;
  }

  f32x16 o[4] = {};
  float mrun = -1e30f, lrun = 0.f;

  bf16x8 kreg[2], vreg[2];
#pragma unroll
  for (int i = 0; i < 2; ++i) {
    kreg[i] = *(const bf16x8*)(kbase + (size_t)krow[i] * D_ + kc[i] * 8);
    vreg[i] = *(const bf16x8*)(vbase + (size_t)vrow[i] * S_ + vc[i] * 8);
  }
#pragma unroll
  for (int i = 0; i < 2; ++i) {
    *(bf16x8*)(lds + ((krow[i] * 256 + kc[i] * 16) ^ ((krow[i] & 15) << 4))) = kreg[i];
    *(bf16x8*)(lds + 16384 + ((vrow[i] * 128 + vc[i] * 16) ^ ((vrow[i] & 7) << 4))) = vreg[i];
  }
  __syncthreads();

  for (int kt = 0; kt < 32; ++kt) {
    const int cur = kt & 1;
    const char* lKc = lds + cur * 32768;
    const char* lVc = lKc + 16384;

    // T14: issue next tile's global loads early; LDS-write to the OTHER buffer later
    if (kt < 31) {
#pragma unroll
      for (int i = 0; i < 2; ++i) {
        kreg[i] = *(const bf16x8*)(kbase + (size_t)((kt + 1) * 64 + krow[i]) * D_ + kc[i] * 8);
        vreg[i] = *(const bf16x8*)(vbase + (size_t)vrow[i] * S_ + (kt + 1) * 64 + vc[i] * 8);
      }
    }

    f32x16 sc[2] = {};
    __builtin_amdgcn_s_setprio(1);
#pragma unroll
    for (int ks = 0; ks < 8; ++ks) {
#pragma unroll
      for (int T = 0; T < 2; ++T) {
        int row = T * 32 + l31;
        bf16x8 kf = *(const bf16x8*)(lKc + ((row * 256 + ks * 32 + hi * 16) ^ ((row & 15) << 4)));
        sc[T] = __builtin_amdgcn_mfma_f32_32x32x16_bf16(kf, qf[ks], sc[T], 0, 0, 0);
      }
    }
    __builtin_amdgcn_s_setprio(0);

    float pmax = sc[0][0];
#pragma unroll
    for (int r = 1; r < 16; ++r) pmax = fmaxf(pmax, sc[0][r]);
#pragma unroll
    for (int r = 0; r < 16; ++r) pmax = fmaxf(pmax, sc[1][r]);
    pmax = fmaxf(pmax, __shfl_xor(pmax, 32));
    if (__any(pmax > mrun + 8.f)) {   // T13 defer-max
      float mn = fmaxf(mrun, pmax);
      float alpha = __expf(mrun - mn);
      mrun = mn;
      lrun *= alpha;
#pragma unroll
      for (int dt = 0; dt < 4; ++dt)
#pragma unroll
        for (int r = 0; r < 16; ++r) o[dt][r] *= alpha;
    }
    float rs = 0.f;
#pragma unroll
    for (int T = 0; T < 2; ++T)
#pragma unroll
      for (int r = 0; r < 16; ++r) {
        float p = __expf(sc[T][r] - mrun);
        sc[T][r] = p;
        rs += p;
      }
    rs += __shfl_xor(rs, 32);
    lrun += rs;

    bf16x8 pf[4];
#pragma unroll
    for (int T = 0; T < 2; ++T) {
#pragma unroll
      for (int g = 0; g < 2; ++g) {
        u32 a0 = cvtpk(sc[T][8 * g + 0], sc[T][8 * g + 1]);
        u32 a1 = cvtpk(sc[T][8 * g + 2], sc[T][8 * g + 3]);
        u32 a2 = cvtpk(sc[T][8 * g + 4], sc[T][8 * g + 5]);
        u32 a3 = cvtpk(sc[T][8 * g + 6], sc[T][8 * g + 7]);
        u32 x0 = (u32)__shfl_xor((int)a0, 32);
        u32 x1 = (u32)__shfl_xor((int)a1, 32);
        u32 x2 = (u32)__shfl_xor((int)a2, 32);
        u32 x3 = (u32)__shfl_xor((int)a3, 32);
        u32 s0 = hi ? x2 : a0;
        u32 s1 = hi ? x3 : a1;
        u32 s2 = hi ? a2 : x0;
        u32 s3 = hi ? a3 : x1;
        u32x4 w = {s0, s1, s2, s3};
        pf[T * 2 + g] = __builtin_bit_cast(bf16x8, w);
      }
    }

    __builtin_amdgcn_s_setprio(1);
#pragma unroll
    for (int ks2 = 0; ks2 < 4; ++ks2) {
#pragma unroll
      for (int dt = 0; dt < 4; ++dt) {
        int row = dt * 32 + l31;
        bf16x8 vf = *(const bf16x8*)(lVc + ((row * 128 + ks2 * 32 + hi * 16) ^ ((row & 7) << 4)));
        o[dt] = __builtin_amdgcn_mfma_f32_32x32x16_bf16(vf, pf[ks2], o[dt], 0, 0, 0);
      }
    }
    __builtin_amdgcn_s_setprio(0);

    // write next tile into the other buffer (disjoint from current reads)
    if (kt < 31) {
      char* nK = lds + (cur ^ 1) * 32768;
      char* nV = nK + 16384;
#pragma unroll
      for (int i = 0; i < 2; ++i) {
        *(bf16x8*)(nK + ((krow[i] * 256 + kc[i] * 16) ^ ((krow[i] & 15) << 4))) = kreg[i];
        *(bf16x8*)(nV + ((vrow[i] * 128 + vc[i] * 16) ^ ((vrow[i] & 7) << 4))) = vreg[i];
      }
    }
    __syncthreads();
  }

  // epilogue: O^T -> O via per-wave LDS region (8KB each), then coalesced stores
  float inv = 1.0f / lrun;
  char* myreg = lds + wid * 8192;  // [32 q][128 d] bf16, XOR (q&15)<<4 on byte-in-row
#pragma unroll
  for (int dt = 0; dt < 4; ++dt)
#pragma unroll
    for (int t = 0; t < 8; ++t) {
      u32 w = cvtpk(o[dt][2 * t] * inv, o[dt][2 * t + 1] * inv);
      int d0 = dt * 32 + 2 * (t & 1) + 8 * (t >> 1) + 4 * hi;
      *(u32*)(myreg + ((l31 * 256 + d0 * 2) ^ ((l31 & 15) << 4))) = w;
    }
  asm volatile("s_waitcnt lgkmcnt(0)");
  {
    int q = lane >> 1, hf = lane & 1;
    int srow = qt * 256 + wid * 32 + q;
    u16* orow = Ob + ((size_t)(b * S_ + srow)) * HID_ + h * 128 + hf * 64;
#pragma unroll
    for (int i = 0; i < 8; ++i) {
      bf16x8 vv = *(const bf16x8*)(myreg + ((q * 256 + hf * 128 + i * 16) ^ ((q & 15) << 4)));
      *(bf16x8*)(orow + i * 8) = vv;
    }
  }
}

extern "C" void kernel_launch(void* const* d_in, const int* in_sizes, int n_in,
                              void* d_out, int out_size, void* d_ws, size_t ws_size,
                              hipStream_t stream) {
  const float* hs = (const float*)d_in[0];
  const float* cosb = (const float*)d_in[1];
  const float* sinb = (const float*)d_in[2];
  const float* w_qkv = (const float*)d_in[3];
  const float* b_qkv = (const float*)d_in[4];
  const float* w_o = (const float*)d_in[5];
  const float* b_o = (const float*)d_in[6];
  float* out = (float*)d_out;

  char* ws = (char*)d_ws;
  u16* Xb    = (u16*)ws;                          // 16,777,216 B (reused as attn_out)
  u16* Wqkvb = (u16*)(ws + 16777216);             // 12,582,912 B
  u16* Wob   = (u16*)(ws + 29360128);             //  8,388,608 B
  u16* qkvb  = (u16*)(ws + 37748736);             // 25,165,824 B (bf16)
  u16* Qb    = (u16*)(ws + 62914560);             // 16,777,216 B
  u16* Kb    = (u16*)(ws + 79691776);             //  4,194,304 B
  u16* Vt    = (u16*)(ws + 83886080);             //  4,194,304 B  (total 88,080,384 B)
  u16* Ob = Xb;

  hipLaunchKernelGGL(k_cvt3, dim3(2048), dim3(256), 0, stream,
                     hs, Xb, (B_ * S_ * HID_) / 8,
                     w_qkv, Wqkvb, (NQKV_ * HID_) / 8,
                     w_o, Wob, (HID_ * HID_) / 8);
  hipLaunchKernelGGL((k_gemm8p<256, u16>), dim3(NQKV_ / 256, (B_ * S_) / 256), dim3(512), 0, stream,
                     Xb, Wqkvb, b_qkv, qkvb, B_ * S_, NQKV_, HID_);
  hipLaunchKernelGGL(k_rope_split, dim3(B_ * S_), dim3(256), 0, stream, qkvb, cosb, sinb, Qb, Kb, Vt);
  hipLaunchKernelGGL(k_attn, dim3(S_ / 256, B_ * H_), dim3(512), 0, stream, Qb, Kb, Vt, Ob);
  hipLaunchKernelGGL((k_gemm8p<128, float>), dim3(HID_ / 256, (B_ * S_) / 128), dim3(512), 0, stream,
                     Ob, Wob, b_o, out, B_ * S_, HID_, HID_);
}